// Round 5
// baseline (584.860 us; speedup 1.0000x reference)
//
#include <hip/hip_runtime.h>
#include <hip/hip_bf16.h>

// Problem constants (CeptaBlock): B=4,T=2048,D=2048,P=512,K=16,ALPHA=4,R=32
#define B_ 4
#define T_ 2048
#define D_ 2048
#define P_ 512
#define K_ 16
#define ALPHA_ 4
#define R_ 32
#define NE_ 409        // int(0.8*512) -> excitatory count
#define EPS_ 1e-6f
#define G_ 4           // tokens per block-group
#define GRID_ 1024     // 256 CUs x 4 blocks/CU (co-resident by construction:
                       // launch_bounds(256,4) caps VGPR<=128 -> 4 waves/SIMD;
                       // LDS 29.25KB*4=117KB < 160KB)
#define NITER_ 2       // (B*T/G)/GRID = 2048/1024

typedef unsigned short u16;
typedef unsigned int u32;
typedef _Float16 half2_t __attribute__((ext_vector_type(2)));

__device__ __forceinline__ float sigmoidf_(float x) {
  return 1.0f / (1.0f + __expf(-x));
}
__device__ __forceinline__ float bfb2f(u16 u) {
  return __uint_as_float(((u32)u) << 16);
}
__device__ __forceinline__ u16 f2bfb(float f) {
  __hip_bfloat16 h = __float2bfloat16(f);
  return *reinterpret_cast<u16*>(&h);
}
__device__ __forceinline__ u16 f2h(float f) {
  _Float16 h = (_Float16)f;
  return *reinterpret_cast<u16*>(&h);
}
__device__ __forceinline__ u32 packh(float a, float b) {
  half2_t h;
  h.x = (_Float16)a;
  h.y = (_Float16)b;
  return __builtin_bit_cast(u32, h);
}
__device__ __forceinline__ float hlo(u32 u) { return (float)__builtin_bit_cast(half2_t, u).x; }
__device__ __forceinline__ float hhi(u32 u) { return (float)__builtin_bit_cast(half2_t, u).y; }
__device__ __forceinline__ float dot2h(u32 a, u32 b, float c) {
#if __has_builtin(__builtin_amdgcn_fdot2)
  return __builtin_amdgcn_fdot2(__builtin_bit_cast(half2_t, a),
                                __builtin_bit_cast(half2_t, b), c, false);
#else
  half2_t ha = __builtin_bit_cast(half2_t, a);
  half2_t hb = __builtin_bit_cast(half2_t, b);
  return c + (float)ha.x * (float)hb.x + (float)ha.y * (float)hb.y;
#endif
}

// Manual grid barrier: counters zeroed by captured hipMemsetAsync each launch.
// Release: __threadfence (device scope, handles cross-XCD L2 per G16) + atomicAdd.
// Wait: agent-scope atomic poll, bounded spin (wrong-answer instead of hang if
// co-residency assumption ever breaks).
__device__ __forceinline__ void grid_barrier(u32* ctr) {
  __syncthreads();
  if (threadIdx.x == 0) {
    __threadfence();
    atomicAdd(ctr, 1u);
    int spins = 0;
    while (__hip_atomic_load(ctr, __ATOMIC_RELAXED, __HIP_MEMORY_SCOPE_AGENT) < (u32)GRID_ &&
           spins < (1 << 22)) {
      __builtin_amdgcn_s_sleep(8);
      ++spins;
    }
    __threadfence();
  }
  __syncthreads();
}

// ================= fused kernel: scalars | phase1 | scan | phase3 =================
__global__ __launch_bounds__(256, 4) void k_fused(
    const float* __restrict__ x, const float* __restrict__ state,
    const float* __restrict__ g1, const float* __restrict__ g2,
    const int* __restrict__ idx_s, const float* __restrict__ wg_s,
    const int* __restrict__ idx_m, const float* __restrict__ wg_m,
    const float* __restrict__ Wp_s, const float* __restrict__ Wo_s,
    const float* __restrict__ Wp_m, const float* __restrict__ Wo_m,
    const float* __restrict__ U, const float* __restrict__ V,
    const float* __restrict__ Wgt, const float* __restrict__ bg,
    float* __restrict__ wq_s, float* __restrict__ fo_s,
    float* __restrict__ wq_m, float* __restrict__ fo_m,
    u16* __restrict__ Ut16, u16* __restrict__ Wt16,
    float* __restrict__ z, float* __restrict__ lam, float* __restrict__ S,
    u32* __restrict__ bar, float* __restrict__ out) {
  __shared__ u16 h1[G_][D_];        // 16 KB  (reused as h2 in part 3)
  __shared__ u16 tl16[G_][P_];      // 4 KB   f16 t = f*u
  __shared__ u16 fl16[G_][P_];      // 4 KB   f16 f
  __shared__ float red[G_][4];
  __shared__ float zp[G_][R_][4];   // 2 KB
  __shared__ float lp[G_][R_][4];   // 2 KB
  __shared__ float Sl[G_][R_];      // 0.5 KB
  // total ~29.25 KB -> 4 blocks/CU (117 KB of 160)

  int tid = threadIdx.x;
  int bid = blockIdx.x;

  // ---------- part 0: quant-dale scalars + f16 transposed U/Wgate tables ----------
  if (bid < 2) {
    int p = bid * 256 + tid;
    float sgn = (p < NE_) ? 1.0f : -1.0f;
    float a = 0, bb = 0, c = 0, d = 0;
#pragma unroll
    for (int k = 0; k < K_; k++) {
      a += fabsf(Wp_s[p * K_ + k]);
      c += fabsf(Wp_m[p * K_ + k]);
    }
#pragma unroll
    for (int k = 0; k < ALPHA_; k++) {
      bb += fabsf(Wo_s[p * ALPHA_ + k]);
      d += fabsf(Wo_m[p * ALPHA_ + k]);
    }
    wq_s[p] = sgn * a * (1.0f / K_);
    fo_s[p] = sgn * bb * (1.0f / ALPHA_);
    wq_m[p] = sgn * c * (1.0f / K_);
    fo_m[p] = sgn * d * (1.0f / ALPHA_);
#pragma unroll
    for (int r = 0; r < R_; r++) {
      Ut16[r * P_ + p] = f2h(U[p * R_ + r]);
      Wt16[r * P_ + p] = f2h(Wgt[p * R_ + r]);
    }
  }
  grid_barrier(bar + 0);

  // ---------- part 1: rmsnorm1 + gather + perceptron + z/lam ----------
  u32 freg[NITER_][G_];  // packed f16 (f at p0, f at p0+1), carried to part 3
#pragma unroll
  for (int it = 0; it < NITER_; ++it) {
    int grp = bid + it * GRID_;
    int token0 = grp * G_;
    int b = token0 >> 11;
    int t0 = token0 & (T_ - 1);
    __syncthreads();

    // stage A: load x, write h1raw = bf16(x*g1) + ss partials (inv deferred)
    float gv[8];
    {
      const float4* gp = reinterpret_cast<const float4*>(g1 + tid * 8);
      *reinterpret_cast<float4*>(&gv[0]) = gp[0];
      *reinterpret_cast<float4*>(&gv[4]) = gp[1];
    }
#pragma unroll
    for (int tok = 0; tok < G_; tok++) {
      float xv[8];
      const float4* xp = reinterpret_cast<const float4*>(x + (size_t)(token0 + tok) * D_ + tid * 8);
      *reinterpret_cast<float4*>(&xv[0]) = xp[0];
      *reinterpret_cast<float4*>(&xv[4]) = xp[1];
      float ss = 0;
      u16 tmp[8];
#pragma unroll
      for (int i = 0; i < 8; i++) { ss += xv[i] * xv[i]; tmp[i] = f2bfb(xv[i] * gv[i]); }
      *reinterpret_cast<uint4*>(&h1[tok][tid * 8]) = *reinterpret_cast<const uint4*>(tmp);
#pragma unroll
      for (int off = 32; off; off >>= 1) ss += __shfl_down(ss, off);
      if ((tid & 63) == 0) red[tok][tid >> 6] = ss;
    }
    __syncthreads();

    float inv[G_];
#pragma unroll
    for (int tok = 0; tok < G_; tok++)
      inv[tok] = rsqrtf((red[tok][0] + red[tok][1] + red[tok][2] + red[tok][3]) * (1.0f / D_) + EPS_);

    // stage B: perceptron for p0=2*tid, p1=p0+1 (aligned with part-3 p-mapping)
    {
      int p0 = 2 * tid, p1 = p0 + 1;
      union { int4 v[4]; int s[16]; } iu0, iu1;
      union { float4 v[4]; float s[16]; } wu0, wu1;
      const int4* ip0 = reinterpret_cast<const int4*>(idx_s + p0 * K_);
      const int4* ip1 = reinterpret_cast<const int4*>(idx_s + p1 * K_);
      const float4* wp0 = reinterpret_cast<const float4*>(wg_s + p0 * K_);
      const float4* wp1 = reinterpret_cast<const float4*>(wg_s + p1 * K_);
#pragma unroll
      for (int q = 0; q < 4; q++) { iu0.v[q] = ip0[q]; iu1.v[q] = ip1[q]; wu0.v[q] = wp0[q]; wu1.v[q] = wp1[q]; }
      float2 wq2 = *reinterpret_cast<const float2*>(wq_s + p0);
#pragma unroll
      for (int tok = 0; tok < G_; tok++) {
        float acc0 = 0, acc1 = 0;
#pragma unroll
        for (int k = 0; k < K_; k++) {
          acc0 += bfb2f(h1[tok][iu0.s[k]]) * wu0.s[k];
          acc1 += bfb2f(h1[tok][iu1.s[k]]) * wu1.s[k];
        }
        float u0 = wq2.x * inv[tok] * acc0, u1 = wq2.y * inv[tok] * acc1;
        float f0 = sigmoidf_(u0), f1 = sigmoidf_(u1);
        *reinterpret_cast<u32*>(&tl16[tok][p0]) = packh(f0 * u0, f1 * u1);
        u32 fp = packh(f0, f1);
        *reinterpret_cast<u32*>(&fl16[tok][p0]) = fp;
        freg[it][tok] = fp;   // carried in regs to part 3 (no f_ssm round trip)
      }
    }
    __syncthreads();

    // stage C: z = t@U, lam = sigmoid(f@Wgt + b) via v_dot2_f32_f16
    int r = tid & 31, pg = tid >> 5;  // 32 r x 8 p-groups of 64
    float zs[G_], ls[G_];
#pragma unroll
    for (int tok = 0; tok < G_; tok++) { zs[tok] = 0; ls[tok] = 0; }
    int pb = pg * 64;
    const uint4* Utp = reinterpret_cast<const uint4*>(Ut16 + r * P_ + pb);
    const uint4* Wtp = reinterpret_cast<const uint4*>(Wt16 + r * P_ + pb);
#pragma unroll
    for (int q = 0; q < 8; q++) {
      uint4 uq = Utp[q];
      uint4 wq4 = Wtp[q];
#pragma unroll
      for (int tok = 0; tok < G_; tok++) {
        uint4 tq = *reinterpret_cast<const uint4*>(&tl16[tok][pb + q * 8]);
        uint4 fq = *reinterpret_cast<const uint4*>(&fl16[tok][pb + q * 8]);
        zs[tok] = dot2h(tq.x, uq.x, zs[tok]);
        zs[tok] = dot2h(tq.y, uq.y, zs[tok]);
        zs[tok] = dot2h(tq.z, uq.z, zs[tok]);
        zs[tok] = dot2h(tq.w, uq.w, zs[tok]);
        ls[tok] = dot2h(fq.x, wq4.x, ls[tok]);
        ls[tok] = dot2h(fq.y, wq4.y, ls[tok]);
        ls[tok] = dot2h(fq.z, wq4.z, ls[tok]);
        ls[tok] = dot2h(fq.w, wq4.w, ls[tok]);
      }
    }
#pragma unroll
    for (int tok = 0; tok < G_; tok++) {
      zs[tok] += __shfl_down(zs[tok], 32);
      ls[tok] += __shfl_down(ls[tok], 32);
    }
    int wid = tid >> 6;
    if ((tid & 63) < 32) {
#pragma unroll
      for (int tok = 0; tok < G_; tok++) { zp[tok][r][wid] = zs[tok]; lp[tok][r][wid] = ls[tok]; }
    }
    __syncthreads();
    if (tid < R_) {
      float bgr = bg[tid];
      float z4[G_], l4[G_];
#pragma unroll
      for (int tok = 0; tok < G_; tok++) {
        float zz = zp[tok][tid][0] + zp[tok][tid][1] + zp[tok][tid][2] + zp[tok][tid][3];
        float ll = lp[tok][tid][0] + lp[tok][tid][1] + lp[tok][tid][2] + lp[tok][tid][3];
        z4[tok] = zz;
        l4[tok] = sigmoidf_(ll + bgr);
      }
      size_t o = ((size_t)(b * R_ + tid)) * T_ + t0;
      *reinterpret_cast<float4*>(&z[o]) = *reinterpret_cast<const float4*>(z4);
      *reinterpret_cast<float4*>(&lam[o]) = *reinterpret_cast<const float4*>(l4);
    }
  }
  grid_barrier(bar + 1);

  // ---------- part 2: parallel linear scan over T (one wave per (b,r)) ----------
  {
    int gw = bid * 4 + (tid >> 6);   // global wave id; blocks 0..31 active
    if (bid < 32 && gw < B_ * R_) {
      int br = gw;
      int lane = tid & 63;           // 64 lanes, 32 timesteps each
      const float* zr = z + (size_t)br * T_ + lane * 32;
      const float* lr = lam + (size_t)br * T_ + lane * 32;
      float zb[32], lb[32];
#pragma unroll
      for (int i = 0; i < 32; i += 4) {
        *reinterpret_cast<float4*>(&zb[i]) = *reinterpret_cast<const float4*>(&zr[i]);
        *reinterpret_cast<float4*>(&lb[i]) = *reinterpret_cast<const float4*>(&lr[i]);
      }
      float A = 1.0f, Z = 0.0f;
#pragma unroll
      for (int i = 0; i < 32; i++) { Z = lb[i] * Z + zb[i]; A *= lb[i]; }
      for (int off = 1; off < 64; off <<= 1) {
        float Ap = __shfl_up(A, off);
        float Zp = __shfl_up(Z, off);
        if (lane >= off) { Z = A * Zp + Z; A = A * Ap; }
      }
      float s0 = state[br];
      float Ae = __shfl_up(A, 1);
      float Ze = __shfl_up(Z, 1);
      float s = (lane == 0) ? s0 : (Ae * s0 + Ze);
      float sb[32];
#pragma unroll
      for (int i = 0; i < 32; i++) { s = lb[i] * s + zb[i]; sb[i] = s; }
      float* Sr = S + (size_t)br * T_ + lane * 32;
#pragma unroll
      for (int i = 0; i < 32; i += 4)
        *reinterpret_cast<float4*>(&Sr[i]) = *reinterpret_cast<const float4*>(&sb[i]);
      if (lane == 63) out[(size_t)B_ * T_ * D_ + br] = s;  // new_state
    }
  }
  grid_barrier(bar + 2);

  // ---------- part 3: tilde=S@V, y_ssm, x_after, rmsnorm2, MLP, out ----------
#pragma unroll
  for (int it = 0; it < NITER_; ++it) {
    int grp = bid + it * GRID_;
    int token0 = grp * G_;
    int b = token0 >> 11;
    int t0 = token0 & (T_ - 1);
    int p0 = 2 * tid;
    __syncthreads();
    if (tid < G_ * R_) {
      int tok = tid >> 5, r = tid & 31;
      Sl[tok][r] = S[((size_t)(b * R_ + r)) * T_ + t0 + tok];
    }
    __syncthreads();

    // tilde = S @ V (scalar Sl broadcasts, low VGPR)
    float til0[G_], til1[G_];
#pragma unroll
    for (int tok = 0; tok < G_; tok++) { til0[tok] = 0; til1[tok] = 0; }
#pragma unroll 4
    for (int r = 0; r < R_; r++) {
      float2 vv = *reinterpret_cast<const float2*>(V + r * P_ + p0);
#pragma unroll
      for (int tok = 0; tok < G_; tok++) {
        float s = Sl[tok][r];
        til0[tok] += s * vv.x;
        til1[tok] += s * vv.y;
      }
    }

    float2 fo = *reinterpret_cast<const float2*>(fo_s + p0);
    float gv[8];
    {
      const float4* gp = reinterpret_cast<const float4*>(g2 + tid * 8);
      *reinterpret_cast<float4*>(&gv[0]) = gp[0];
      *reinterpret_cast<float4*>(&gv[4]) = gp[1];
    }

    // xa = x + y_ssm; ss partials; h2raw = bf16(xa*g2) (inv deferred)
    float xa[G_][8];
#pragma unroll
    for (int tok = 0; tok < G_; tok++) {
      u32 fp = freg[it][tok];
      float val0 = hlo(fp) * til0[tok] * fo.x;
      float val1 = hhi(fp) * til1[tok] * fo.y;
      float xv[8];
      const float4* xp = reinterpret_cast<const float4*>(x + (size_t)(token0 + tok) * D_ + tid * 8);
      *reinterpret_cast<float4*>(&xv[0]) = xp[0];
      *reinterpret_cast<float4*>(&xv[4]) = xp[1];
      float ss = 0;
#pragma unroll
      for (int a = 0; a < 4; a++) {
        float v0 = xv[a] + val0;
        float v1 = xv[4 + a] + val1;
        xa[tok][a] = v0;
        xa[tok][4 + a] = v1;
        ss += v0 * v0 + v1 * v1;
      }
      u16 tmp[8];
#pragma unroll
      for (int i = 0; i < 8; i++) tmp[i] = f2bfb(xa[tok][i] * gv[i]);
      *reinterpret_cast<uint4*>(&h1[tok][tid * 8]) = *reinterpret_cast<const uint4*>(tmp);
#pragma unroll
      for (int off = 32; off; off >>= 1) ss += __shfl_down(ss, off);
      if ((tid & 63) == 0) red[tok][tid >> 6] = ss;
    }
    __syncthreads();

    // MLP gather (weights loaded here, short live range)
    union { int4 v[4]; int s[16]; } iu0, iu1;
    union { float4 v[4]; float s[16]; } wu0, wu1;
    {
      const int4* ip0 = reinterpret_cast<const int4*>(idx_m + p0 * K_);
      const int4* ip1 = reinterpret_cast<const int4*>(idx_m + (p0 + 1) * K_);
      const float4* wp0 = reinterpret_cast<const float4*>(wg_m + p0 * K_);
      const float4* wp1 = reinterpret_cast<const float4*>(wg_m + (p0 + 1) * K_);
#pragma unroll
      for (int q = 0; q < 4; q++) { iu0.v[q] = ip0[q]; iu1.v[q] = ip1[q]; wu0.v[q] = wp0[q]; wu1.v[q] = wp1[q]; }
    }
    float2 wqm = *reinterpret_cast<const float2*>(wq_m + p0);
    float2 fom = *reinterpret_cast<const float2*>(fo_m + p0);

#pragma unroll
    for (int tok = 0; tok < G_; tok++) {
      float invt = rsqrtf((red[tok][0] + red[tok][1] + red[tok][2] + red[tok][3]) * (1.0f / D_) + EPS_);
      float acc0 = 0, acc1 = 0;
#pragma unroll
      for (int k = 0; k < K_; k++) {
        acc0 += bfb2f(h1[tok][iu0.s[k]]) * wu0.s[k];
        acc1 += bfb2f(h1[tok][iu1.s[k]]) * wu1.s[k];
      }
      float u0 = wqm.x * invt * acc0, u1 = wqm.y * invt * acc1;
      float f0 = sigmoidf_(u0), f1 = sigmoidf_(u1);
      float val0 = f0 * u0 * fom.x, val1 = f1 * u1 * fom.y;
      float ov[8];
#pragma unroll
      for (int a = 0; a < 4; a++) {
        ov[a] = xa[tok][a] + val0;
        ov[4 + a] = xa[tok][4 + a] + val1;
      }
      float4* op = reinterpret_cast<float4*>(out + (size_t)(token0 + tok) * D_ + tid * 8);
      op[0] = *reinterpret_cast<const float4*>(&ov[0]);
      op[1] = *reinterpret_cast<const float4*>(&ov[4]);
    }
  }
}

// ---------------- host ----------------
extern "C" void kernel_launch(void* const* d_in, const int* in_sizes, int n_in,
                              void* d_out, int out_size, void* d_ws, size_t ws_size,
                              hipStream_t stream) {
  const float* x     = (const float*)d_in[0];
  const float* state = (const float*)d_in[1];
  const float* g1    = (const float*)d_in[2];
  const float* g2    = (const float*)d_in[3];
  const int*   idx_s = (const int*)d_in[4];
  const float* wg_s  = (const float*)d_in[5];
  const int*   idx_m = (const int*)d_in[6];
  const float* wg_m  = (const float*)d_in[7];
  const float* Wp_s  = (const float*)d_in[8];
  const float* Wo_s  = (const float*)d_in[9];
  const float* Wp_m  = (const float*)d_in[10];
  const float* Wo_m  = (const float*)d_in[11];
  const float* U     = (const float*)d_in[12];
  const float* V     = (const float*)d_in[13];
  const float* Wgt   = (const float*)d_in[14];
  const float* bg    = (const float*)d_in[15];
  float* out = (float*)d_out;

  char* ws = (char*)d_ws;
  float* wq_s = (float*)(ws + 0);
  float* fo_s = (float*)(ws + 2048);
  float* wq_m = (float*)(ws + 4096);
  float* fo_m = (float*)(ws + 6144);
  u16* Ut16 = (u16*)(ws + 8192);                     // 32 KB f16 U^T [R][P]
  u16* Wt16 = (u16*)(ws + 8192 + 32768);             // 32 KB f16 Wgate^T [R][P]
  size_t off = 8192 + 65536;
  float* z   = (float*)(ws + off); off += (size_t)B_ * R_ * T_ * 4;  // 1 MB
  float* lam = (float*)(ws + off); off += (size_t)B_ * R_ * T_ * 4;  // 1 MB
  float* S   = (float*)(ws + off); off += (size_t)B_ * R_ * T_ * 4;  // 1 MB
  u32* bar   = (u32*)(ws + off);                                     // barrier counters

  // zero the barrier counters (captured into the graph, runs every iteration)
  hipMemsetAsync(bar, 0, 256, stream);

  hipLaunchKernelGGL(k_fused, dim3(GRID_), dim3(256), 0, stream,
                     x, state, g1, g2, idx_s, wg_s, idx_m, wg_m,
                     Wp_s, Wo_s, Wp_m, Wo_m, U, V, Wgt, bg,
                     wq_s, fo_s, wq_m, fo_m, Ut16, Wt16,
                     z, lam, S, bar, out);
}

// Round 6
// 308.391 us; speedup vs baseline: 1.8965x; 1.8965x over previous
//
#include <hip/hip_runtime.h>
#include <hip/hip_bf16.h>

// Problem constants (CeptaBlock): B=4,T=2048,D=2048,P=512,K=16,ALPHA=4,R=32
#define B_ 4
#define T_ 2048
#define D_ 2048
#define P_ 512
#define K_ 16
#define ALPHA_ 4
#define R_ 32
#define NE_ 409        // int(0.8*512) -> excitatory count
#define EPS_ 1e-6f
#define G_ 4           // tokens per block-group
#define GRID_ 1024     // 256 CUs x 4 blocks/CU (co-resident: VGPR<=128 via
                       // launch_bounds(256,4); LDS ~28.8KB*4=115KB<160KB)
#define NITER_ 2       // (B*T/G)/GRID

typedef unsigned short u16;
typedef unsigned int u32;

__device__ __forceinline__ float sigmoidf_(float x) {
  return 1.0f / (1.0f + __expf(-x));
}
__device__ __forceinline__ float bfb2f(u16 u) {
  return __uint_as_float(((u32)u) << 16);
}
__device__ __forceinline__ u16 f2bfb(float f) {
  __hip_bfloat16 h = __float2bfloat16(f);
  return *reinterpret_cast<u16*>(&h);
}
__device__ __forceinline__ float bflo(u32 u) { return __uint_as_float(u << 16); }
__device__ __forceinline__ float bfhi(u32 u) { return __uint_as_float(u & 0xFFFF0000u); }

// Coherent (L2-bypassing, agent-scope) scalar accessors: data written this way
// is visible cross-XCD at the coherent point with NO buffer_wbl2/buffer_inv.
__device__ __forceinline__ void cstore(float* p, float v) {
  __hip_atomic_store(p, v, __ATOMIC_RELAXED, __HIP_MEMORY_SCOPE_AGENT);
}
__device__ __forceinline__ float cload(const float* p) {
  return __hip_atomic_load(p, __ATOMIC_RELAXED, __HIP_MEMORY_SCOPE_AGENT);
}

// Fence-free grid barrier. All inter-block data moves via cstore/cload (sc0 sc1),
// so no cache maintenance is needed -- only completion (s_waitcnt vmcnt(0))
// before publishing arrival. 16 cacheline-spread arrive counters; block 0 is the
// master: polls the sum, then sets 16 spread release flags. Others poll one flag
// with s_sleep backoff. Bounded spins => wrong answer instead of hang if the
// co-residency assumption ever breaks.
__device__ __forceinline__ void gbar(u32* region, int bid, int tid) {
  u32* arrive = region;          // 16 counters spaced 16 u32 (64 B)
  u32* flag = region + 256;      // 16 flags spaced 16 u32
  __syncthreads();
  if (tid == 0) {
    asm volatile("s_waitcnt vmcnt(0)" ::: "memory");
    atomicAdd(&arrive[(bid & 15) << 4], 1u);
    if (bid == 0) {
      int spins = 0;
      for (;;) {
        u32 s = 0;
#pragma unroll
        for (int i = 0; i < 16; i++)
          s += __hip_atomic_load(&arrive[i << 4], __ATOMIC_RELAXED, __HIP_MEMORY_SCOPE_AGENT);
        if (s >= (u32)GRID_ || ++spins > (1 << 22)) break;
        __builtin_amdgcn_s_sleep(2);
      }
#pragma unroll
      for (int i = 0; i < 16; i++)
        __hip_atomic_store(&flag[i << 4], 1u, __ATOMIC_RELAXED, __HIP_MEMORY_SCOPE_AGENT);
    } else {
      int spins = 0;
      while (__hip_atomic_load(&flag[(bid & 15) << 4], __ATOMIC_RELAXED,
                               __HIP_MEMORY_SCOPE_AGENT) == 0 &&
             ++spins < (1 << 22))
        __builtin_amdgcn_s_sleep(16);
    }
    asm volatile("" ::: "memory");
  }
  __syncthreads();
}

// ================= fused kernel: phase1 | scan | phase3 =================
__global__ __launch_bounds__(256, 4) void k_fused(
    const float* __restrict__ x, const float* __restrict__ state,
    const float* __restrict__ g1, const float* __restrict__ g2,
    const int* __restrict__ idx_s, const float* __restrict__ wg_s,
    const int* __restrict__ idx_m, const float* __restrict__ wg_m,
    const float* __restrict__ Wp_s, const float* __restrict__ Wo_s,
    const float* __restrict__ Wp_m, const float* __restrict__ Wo_m,
    const float* __restrict__ U, const float* __restrict__ V,
    const float* __restrict__ Wgt, const float* __restrict__ bg,
    float* __restrict__ z, float* __restrict__ lam, float* __restrict__ S,
    u32* __restrict__ bar, float* __restrict__ out) {
  __shared__ u16 h1[G_][D_];        // 16 KB  bf16(x*g) (reused as h2 in part 3)
  __shared__ u32 tf[G_][P_];        // 8 KB   packed (f<<16)|t  bf16x2
  __shared__ float red[G_][4];
  __shared__ float zp[G_][R_][4];   // 2 KB
  __shared__ float lp[G_][R_][4];   // 2 KB
  __shared__ float Sl[G_][R_];      // 0.5 KB
  // total ~28.8 KB -> 4 blocks/CU (115 KB of 160)

  int tid = threadIdx.x;
  int bid = blockIdx.x;

  // ---------- part 1: rmsnorm1 + gather + perceptron + z/lam ----------
  u32 freg[NITER_][G_];  // packed bf16 (f at p0, f at p0+1), carried to part 3
#pragma unroll
  for (int it = 0; it < NITER_; ++it) {
    int grp = bid + it * GRID_;
    int token0 = grp * G_;
    int b = token0 >> 11;
    int t0 = token0 & (T_ - 1);
    __syncthreads();

    // stage A: load x, write h1raw = bf16(x*g1) + ss partials (inv deferred)
    float gv[8];
    {
      const float4* gp = reinterpret_cast<const float4*>(g1 + tid * 8);
      *reinterpret_cast<float4*>(&gv[0]) = gp[0];
      *reinterpret_cast<float4*>(&gv[4]) = gp[1];
    }
#pragma unroll
    for (int tok = 0; tok < G_; tok++) {
      float xv[8];
      const float4* xp = reinterpret_cast<const float4*>(x + (size_t)(token0 + tok) * D_ + tid * 8);
      *reinterpret_cast<float4*>(&xv[0]) = xp[0];
      *reinterpret_cast<float4*>(&xv[4]) = xp[1];
      float ss = 0;
      u16 tmp[8];
#pragma unroll
      for (int i = 0; i < 8; i++) { ss += xv[i] * xv[i]; tmp[i] = f2bfb(xv[i] * gv[i]); }
      *reinterpret_cast<uint4*>(&h1[tok][tid * 8]) = *reinterpret_cast<const uint4*>(tmp);
#pragma unroll
      for (int off = 32; off; off >>= 1) ss += __shfl_down(ss, off);
      if ((tid & 63) == 0) red[tok][tid >> 6] = ss;
    }
    __syncthreads();

    float inv[G_];
#pragma unroll
    for (int tok = 0; tok < G_; tok++)
      inv[tok] = rsqrtf((red[tok][0] + red[tok][1] + red[tok][2] + red[tok][3]) * (1.0f / D_) + EPS_);

    // stage B: perceptron for p0=2*tid, p1=p0+1; wq computed inline from Wp_s
    {
      int p0 = 2 * tid, p1 = p0 + 1;
      union { int4 v[4]; int s[16]; } iu0, iu1;
      union { float4 v[4]; float s[16]; } wu0, wu1;
      const int4* ip0 = reinterpret_cast<const int4*>(idx_s + p0 * K_);
      const int4* ip1 = reinterpret_cast<const int4*>(idx_s + p1 * K_);
      const float4* wp0 = reinterpret_cast<const float4*>(wg_s + p0 * K_);
      const float4* wp1 = reinterpret_cast<const float4*>(wg_s + p1 * K_);
#pragma unroll
      for (int q = 0; q < 4; q++) { iu0.v[q] = ip0[q]; iu1.v[q] = ip1[q]; wu0.v[q] = wp0[q]; wu1.v[q] = wp1[q]; }
      float aw0 = 0, aw1 = 0;
      {
        const float4* q0 = reinterpret_cast<const float4*>(Wp_s + p0 * K_);
        const float4* q1 = reinterpret_cast<const float4*>(Wp_s + p1 * K_);
#pragma unroll
        for (int q = 0; q < 4; q++) {
          float4 wa = q0[q], wb = q1[q];
          aw0 += fabsf(wa.x) + fabsf(wa.y) + fabsf(wa.z) + fabsf(wa.w);
          aw1 += fabsf(wb.x) + fabsf(wb.y) + fabsf(wb.z) + fabsf(wb.w);
        }
      }
      float wq0 = ((p0 < NE_) ? 1.0f : -1.0f) * aw0 * (1.0f / K_);
      float wq1 = ((p1 < NE_) ? 1.0f : -1.0f) * aw1 * (1.0f / K_);
#pragma unroll
      for (int tok = 0; tok < G_; tok++) {
        float acc0 = 0, acc1 = 0;
#pragma unroll
        for (int k = 0; k < K_; k++) {
          acc0 += bfb2f(h1[tok][iu0.s[k]]) * wu0.s[k];
          acc1 += bfb2f(h1[tok][iu1.s[k]]) * wu1.s[k];
        }
        float u0 = wq0 * inv[tok] * acc0, u1 = wq1 * inv[tok] * acc1;
        float f0 = sigmoidf_(u0), f1 = sigmoidf_(u1);
        tf[tok][p0 >> 1] = 0;  // placeholder overwritten below (keeps index math obvious)
        // packed per-p bf16 (t,f); layout [p] so stage C reads 4 consecutive p's
        *reinterpret_cast<u32*>(&tf[tok][p0]) = 0;  // not used; real writes below
        tf[tok][p0] = ((u32)f2bfb(f0) << 16) | (u32)f2bfb(f0 * u0);
        tf[tok][p1] = ((u32)f2bfb(f1) << 16) | (u32)f2bfb(f1 * u1);
        freg[it][tok] = ((u32)f2bfb(f1) << 16) | (u32)f2bfb(f0);
      }
    }
    __syncthreads();

    // stage C: z = t@U, lam = sigmoid(f@Wgt + b); U/Wgt direct f32 (L2-hot inputs)
    int r = tid & 31, pg = tid >> 5;  // 32 r x 8 p-groups of 64
    float zs[G_], ls[G_];
#pragma unroll
    for (int tok = 0; tok < G_; tok++) { zs[tok] = 0; ls[tok] = 0; }
    int pb = pg * 64;
#pragma unroll 2
    for (int pq = 0; pq < 16; pq++) {
      int p = pb + pq * 4;
      float u0 = U[(p + 0) * R_ + r], u1 = U[(p + 1) * R_ + r];
      float u2 = U[(p + 2) * R_ + r], u3 = U[(p + 3) * R_ + r];
      float w0 = Wgt[(p + 0) * R_ + r], w1 = Wgt[(p + 1) * R_ + r];
      float w2 = Wgt[(p + 2) * R_ + r], w3 = Wgt[(p + 3) * R_ + r];
#pragma unroll
      for (int tok = 0; tok < G_; tok++) {
        uint4 q = *reinterpret_cast<const uint4*>(&tf[tok][p]);
        zs[tok] += bflo(q.x) * u0 + bflo(q.y) * u1 + bflo(q.z) * u2 + bflo(q.w) * u3;
        ls[tok] += bfhi(q.x) * w0 + bfhi(q.y) * w1 + bfhi(q.z) * w2 + bfhi(q.w) * w3;
      }
    }
#pragma unroll
    for (int tok = 0; tok < G_; tok++) {
      zs[tok] += __shfl_down(zs[tok], 32);
      ls[tok] += __shfl_down(ls[tok], 32);
    }
    int wid = tid >> 6;
    if ((tid & 63) < 32) {
#pragma unroll
      for (int tok = 0; tok < G_; tok++) { zp[tok][r][wid] = zs[tok]; lp[tok][r][wid] = ls[tok]; }
    }
    __syncthreads();
    if (tid < R_) {
      float bgr = bg[tid];
      size_t o = ((size_t)(b * R_ + tid)) * T_ + t0;
#pragma unroll
      for (int tok = 0; tok < G_; tok++) {
        float zz = zp[tok][tid][0] + zp[tok][tid][1] + zp[tok][tid][2] + zp[tok][tid][3];
        float ll = lp[tok][tid][0] + lp[tok][tid][1] + lp[tok][tid][2] + lp[tok][tid][3];
        cstore(&z[o + tok], zz);                      // coherent: crosses XCDs
        cstore(&lam[o + tok], sigmoidf_(ll + bgr));
      }
    }
  }
  gbar(bar, bid, tid);

  // ---------- part 2: parallel linear scan over T (one wave per (b,r)) ----------
  if (bid < 32) {
    int br = bid * 4 + (tid >> 6);   // global wave id, 128 total
    int lane = tid & 63;             // 64 lanes, 32 timesteps each
    const float* zr = z + (size_t)br * T_ + lane * 32;
    const float* lr = lam + (size_t)br * T_ + lane * 32;
    float zb[32], lb[32];
#pragma unroll
    for (int i = 0; i < 32; i++) { zb[i] = cload(&zr[i]); lb[i] = cload(&lr[i]); }
    float A = 1.0f, Z = 0.0f;
#pragma unroll
    for (int i = 0; i < 32; i++) { Z = lb[i] * Z + zb[i]; A *= lb[i]; }
    for (int off = 1; off < 64; off <<= 1) {
      float Ap = __shfl_up(A, off);
      float Zp = __shfl_up(Z, off);
      if (lane >= off) { Z = A * Zp + Z; A = A * Ap; }
    }
    float s0 = state[br];
    float Ae = __shfl_up(A, 1);
    float Ze = __shfl_up(Z, 1);
    float s = (lane == 0) ? s0 : (Ae * s0 + Ze);
    float* Sr = S + (size_t)br * T_ + lane * 32;
#pragma unroll
    for (int i = 0; i < 32; i++) { s = lb[i] * s + zb[i]; cstore(&Sr[i], s); }
    if (lane == 63) out[(size_t)B_ * T_ * D_ + br] = s;  // new_state (host-read)
  }
  gbar(bar + 512, bid, tid);

  // ---------- part 3: tilde=S@V, y_ssm, x_after, rmsnorm2, MLP, out ----------
#pragma unroll
  for (int it = 0; it < NITER_; ++it) {
    int grp = bid + it * GRID_;
    int token0 = grp * G_;
    int b = token0 >> 11;
    int t0 = token0 & (T_ - 1);
    int p0 = 2 * tid, p1 = p0 + 1;
    __syncthreads();
    if (tid < G_ * R_) {
      int tok = tid >> 5, r = tid & 31;
      Sl[tok][r] = cload(&S[((size_t)(b * R_ + r)) * T_ + t0 + tok]);
    }
    __syncthreads();

    // tilde = S @ V (scalar Sl broadcasts, low VGPR)
    float til0[G_], til1[G_];
#pragma unroll
    for (int tok = 0; tok < G_; tok++) { til0[tok] = 0; til1[tok] = 0; }
#pragma unroll 4
    for (int r = 0; r < R_; r++) {
      float2 vv = *reinterpret_cast<const float2*>(V + r * P_ + p0);
#pragma unroll
      for (int tok = 0; tok < G_; tok++) {
        float s = Sl[tok][r];
        til0[tok] += s * vv.x;
        til1[tok] += s * vv.y;
      }
    }

    // fo (Wout_ssm quant scale) inline: short live range
    float sgn0 = (p0 < NE_) ? 1.0f : -1.0f;
    float sgn1 = (p1 < NE_) ? 1.0f : -1.0f;
    float fo0, fo1;
    {
      float4 a = *reinterpret_cast<const float4*>(Wo_s + p0 * ALPHA_);
      float4 c = *reinterpret_cast<const float4*>(Wo_s + p1 * ALPHA_);
      fo0 = sgn0 * 0.25f * (fabsf(a.x) + fabsf(a.y) + fabsf(a.z) + fabsf(a.w));
      fo1 = sgn1 * 0.25f * (fabsf(c.x) + fabsf(c.y) + fabsf(c.z) + fabsf(c.w));
    }
    float gv[8];
    {
      const float4* gp = reinterpret_cast<const float4*>(g2 + tid * 8);
      *reinterpret_cast<float4*>(&gv[0]) = gp[0];
      *reinterpret_cast<float4*>(&gv[4]) = gp[1];
    }

    // xa = x + y_ssm; ss partials; h2raw = bf16(xa*g2) (inv deferred)
    float xa[G_][8];
#pragma unroll
    for (int tok = 0; tok < G_; tok++) {
      u32 fp = freg[it][tok];
      float val0 = bflo(fp) * til0[tok] * fo0;
      float val1 = bfhi(fp) * til1[tok] * fo1;
      float xv[8];
      const float4* xp = reinterpret_cast<const float4*>(x + (size_t)(token0 + tok) * D_ + tid * 8);
      *reinterpret_cast<float4*>(&xv[0]) = xp[0];
      *reinterpret_cast<float4*>(&xv[4]) = xp[1];
      float ss = 0;
#pragma unroll
      for (int a = 0; a < 4; a++) {
        float v0 = xv[a] + val0;
        float v1 = xv[4 + a] + val1;
        xa[tok][a] = v0;
        xa[tok][4 + a] = v1;
        ss += v0 * v0 + v1 * v1;
      }
      u16 tmp[8];
#pragma unroll
      for (int i = 0; i < 8; i++) tmp[i] = f2bfb(xa[tok][i] * gv[i]);
      *reinterpret_cast<uint4*>(&h1[tok][tid * 8]) = *reinterpret_cast<const uint4*>(tmp);
#pragma unroll
      for (int off = 32; off; off >>= 1) ss += __shfl_down(ss, off);
      if ((tid & 63) == 0) red[tok][tid >> 6] = ss;
    }
    __syncthreads();

    // MLP gather; wqm/fom inline from Wp_m/Wo_m (short live range)
    union { int4 v[4]; int s[16]; } iu0, iu1;
    union { float4 v[4]; float s[16]; } wu0, wu1;
    {
      const int4* ip0 = reinterpret_cast<const int4*>(idx_m + p0 * K_);
      const int4* ip1 = reinterpret_cast<const int4*>(idx_m + p1 * K_);
      const float4* wp0 = reinterpret_cast<const float4*>(wg_m + p0 * K_);
      const float4* wp1 = reinterpret_cast<const float4*>(wg_m + p1 * K_);
#pragma unroll
      for (int q = 0; q < 4; q++) { iu0.v[q] = ip0[q]; iu1.v[q] = ip1[q]; wu0.v[q] = wp0[q]; wu1.v[q] = wp1[q]; }
    }
    float wqm0, wqm1, fom0, fom1;
    {
      float aw0 = 0, aw1 = 0;
      const float4* q0 = reinterpret_cast<const float4*>(Wp_m + p0 * K_);
      const float4* q1 = reinterpret_cast<const float4*>(Wp_m + p1 * K_);
#pragma unroll
      for (int q = 0; q < 4; q++) {
        float4 wa = q0[q], wb = q1[q];
        aw0 += fabsf(wa.x) + fabsf(wa.y) + fabsf(wa.z) + fabsf(wa.w);
        aw1 += fabsf(wb.x) + fabsf(wb.y) + fabsf(wb.z) + fabsf(wb.w);
      }
      wqm0 = sgn0 * aw0 * (1.0f / K_);
      wqm1 = sgn1 * aw1 * (1.0f / K_);
      float4 e = *reinterpret_cast<const float4*>(Wo_m + p0 * ALPHA_);
      float4 h = *reinterpret_cast<const float4*>(Wo_m + p1 * ALPHA_);
      fom0 = sgn0 * 0.25f * (fabsf(e.x) + fabsf(e.y) + fabsf(e.z) + fabsf(e.w));
      fom1 = sgn1 * 0.25f * (fabsf(h.x) + fabsf(h.y) + fabsf(h.z) + fabsf(h.w));
    }

#pragma unroll
    for (int tok = 0; tok < G_; tok++) {
      float invt = rsqrtf((red[tok][0] + red[tok][1] + red[tok][2] + red[tok][3]) * (1.0f / D_) + EPS_);
      float acc0 = 0, acc1 = 0;
#pragma unroll
      for (int k = 0; k < K_; k++) {
        acc0 += bfb2f(h1[tok][iu0.s[k]]) * wu0.s[k];
        acc1 += bfb2f(h1[tok][iu1.s[k]]) * wu1.s[k];
      }
      float u0 = wqm0 * invt * acc0, u1 = wqm1 * invt * acc1;
      float f0 = sigmoidf_(u0), f1 = sigmoidf_(u1);
      float val0 = f0 * u0 * fom0, val1 = f1 * u1 * fom1;
      float ov[8];
#pragma unroll
      for (int a = 0; a < 4; a++) {
        ov[a] = xa[tok][a] + val0;
        ov[4 + a] = xa[tok][4 + a] + val1;
      }
      float4* op = reinterpret_cast<float4*>(out + (size_t)(token0 + tok) * D_ + tid * 8);
      op[0] = *reinterpret_cast<const float4*>(&ov[0]);
      op[1] = *reinterpret_cast<const float4*>(&ov[4]);
    }
  }
}

// ---------------- host ----------------
extern "C" void kernel_launch(void* const* d_in, const int* in_sizes, int n_in,
                              void* d_out, int out_size, void* d_ws, size_t ws_size,
                              hipStream_t stream) {
  const float* x     = (const float*)d_in[0];
  const float* state = (const float*)d_in[1];
  const float* g1    = (const float*)d_in[2];
  const float* g2    = (const float*)d_in[3];
  const int*   idx_s = (const int*)d_in[4];
  const float* wg_s  = (const float*)d_in[5];
  const int*   idx_m = (const int*)d_in[6];
  const float* wg_m  = (const float*)d_in[7];
  const float* Wp_s  = (const float*)d_in[8];
  const float* Wo_s  = (const float*)d_in[9];
  const float* Wp_m  = (const float*)d_in[10];
  const float* Wo_m  = (const float*)d_in[11];
  const float* U     = (const float*)d_in[12];
  const float* V     = (const float*)d_in[13];
  const float* Wgt   = (const float*)d_in[14];
  const float* bg    = (const float*)d_in[15];
  float* out = (float*)d_out;

  char* ws = (char*)d_ws;
  float* z   = (float*)(ws);                                          // 1 MB
  float* lam = (float*)(ws + (size_t)B_ * R_ * T_ * 4);               // 1 MB
  float* S   = (float*)(ws + 2 * (size_t)B_ * R_ * T_ * 4);           // 1 MB
  u32* bar   = (u32*)(ws + 3 * (size_t)B_ * R_ * T_ * 4);             // 2 x 2 KB

  // zero both barrier regions (captured into the graph, runs every iteration)
  hipMemsetAsync(bar, 0, 2 * 512 * sizeof(u32), stream);

  hipLaunchKernelGGL(k_fused, dim3(GRID_), dim3(256), 0, stream,
                     x, state, g1, g2, idx_s, wg_s, idx_m, wg_m,
                     Wp_s, Wo_s, Wp_m, Wo_m, U, V, Wgt, bg,
                     z, lam, S, bar, out);
}

// Round 7
// 208.417 us; speedup vs baseline: 2.8062x; 1.4797x over previous
//
#include <hip/hip_runtime.h>
#include <hip/hip_bf16.h>

// Problem constants (CeptaBlock): B=4,T=2048,D=2048,P=512,K=16,ALPHA=4,R=32
#define B_ 4
#define T_ 2048
#define D_ 2048
#define P_ 512
#define K_ 16
#define ALPHA_ 4
#define R_ 32
#define NE_ 409        // int(0.8*512) -> excitatory count
#define EPS_ 1e-6f
#define G_ 4           // tokens per block

typedef unsigned short u16;
typedef unsigned int u32;

__device__ __forceinline__ float sigmoidf_(float x) {
  return 1.0f / (1.0f + __expf(-x));
}
__device__ __forceinline__ u16 f2bfb(float f) {
  __hip_bfloat16 h = __float2bfloat16(f);
  return *reinterpret_cast<u16*>(&h);
}
// packed-u32 (2x bf16) helpers: lo16 -> float, hi16 -> float
__device__ __forceinline__ float bflo(u32 u) { return __uint_as_float(u << 16); }
__device__ __forceinline__ float bfhi(u32 u) { return __uint_as_float(u & 0xFFFF0000u); }
__device__ __forceinline__ u32 packbf(float lo, float hi) {
  return ((u32)f2bfb(hi) << 16) | (u32)f2bfb(lo);
}

// ---------------- K0: per-neuron quant-dale scalars ----------------
__global__ void k_scalars(const float* __restrict__ Wp_s, const float* __restrict__ Wo_s,
                          const float* __restrict__ Wp_m, const float* __restrict__ Wo_m,
                          float* __restrict__ wq_s, float* __restrict__ fo_s,
                          float* __restrict__ wq_m, float* __restrict__ fo_m) {
  int p = blockIdx.x * blockDim.x + threadIdx.x;
  if (p >= P_) return;
  float sgn = (p < NE_) ? 1.0f : -1.0f;
  float a = 0, b = 0, c = 0, d = 0;
#pragma unroll
  for (int k = 0; k < K_; k++) {
    a += fabsf(Wp_s[p * K_ + k]);
    c += fabsf(Wp_m[p * K_ + k]);
  }
#pragma unroll
  for (int k = 0; k < ALPHA_; k++) {
    b += fabsf(Wo_s[p * ALPHA_ + k]);
    d += fabsf(Wo_m[p * ALPHA_ + k]);
  }
  wq_s[p] = sgn * a * (1.0f / K_);
  fo_s[p] = sgn * b * (1.0f / ALPHA_);
  wq_m[p] = sgn * c * (1.0f / K_);
  fo_m[p] = sgn * d * (1.0f / ALPHA_);
}

// ---------------- K1: rmsnorm1 + gather + perceptron + z/lam, G_ tokens/block ----------------
// Token-PAIR-packed h1: h1p[pair][d] = (bf16(x_tokB*g)<<16)|bf16(x_tokA*g).
// One ds_read_b32 in the gather feeds BOTH tokens of a pair (128 -> 64 DS ops/thread).
__global__ __launch_bounds__(256) void k_phase1(
    const float* __restrict__ x, const float* __restrict__ g1,
    const int* __restrict__ idx, const float* __restrict__ wg,
    const float* __restrict__ U, const float* __restrict__ Wgt,
    const float* __restrict__ bg, const float* __restrict__ wq,
    u16* __restrict__ f_ssm, float* __restrict__ z, float* __restrict__ lam) {
  __shared__ u32 h1p[2][D_];        // 16 KB  pair-packed bf16 (inv deferred)
  __shared__ u32 tf[G_][P_];        // 8 KB   packed (f<<16)|t  bf16x2
  __shared__ float red[G_][4];
  __shared__ float zp[G_][R_][4];   // 2 KB
  __shared__ float lp[G_][R_][4];   // 2 KB

  int tid = threadIdx.x;
  int token0 = blockIdx.x * G_;
  int b = token0 >> 11;
  int t0 = token0 & (T_ - 1);

  // ---- stage A: load x for token pairs, write packed h1 + ss partials ----
  float gv[8];
  {
    const float4* gp = reinterpret_cast<const float4*>(g1 + tid * 8);
    *reinterpret_cast<float4*>(&gv[0]) = gp[0];
    *reinterpret_cast<float4*>(&gv[4]) = gp[1];
  }
#pragma unroll
  for (int pr = 0; pr < 2; pr++) {
    int ta = 2 * pr, tb = ta + 1;
    float xv0[8], xv1[8];
    const float4* xp0 = reinterpret_cast<const float4*>(x + (size_t)(token0 + ta) * D_ + tid * 8);
    const float4* xp1 = reinterpret_cast<const float4*>(x + (size_t)(token0 + tb) * D_ + tid * 8);
    *reinterpret_cast<float4*>(&xv0[0]) = xp0[0];
    *reinterpret_cast<float4*>(&xv0[4]) = xp0[1];
    *reinterpret_cast<float4*>(&xv1[0]) = xp1[0];
    *reinterpret_cast<float4*>(&xv1[4]) = xp1[1];
    float ss0 = 0, ss1 = 0;
    u32 tmp[8];
#pragma unroll
    for (int i = 0; i < 8; i++) {
      ss0 += xv0[i] * xv0[i];
      ss1 += xv1[i] * xv1[i];
      tmp[i] = packbf(xv0[i] * gv[i], xv1[i] * gv[i]);
    }
    uint4* hp = reinterpret_cast<uint4*>(&h1p[pr][tid * 8]);
    hp[0] = *reinterpret_cast<const uint4*>(&tmp[0]);
    hp[1] = *reinterpret_cast<const uint4*>(&tmp[4]);
#pragma unroll
    for (int off = 32; off; off >>= 1) {
      ss0 += __shfl_down(ss0, off);
      ss1 += __shfl_down(ss1, off);
    }
    if ((tid & 63) == 0) { red[ta][tid >> 6] = ss0; red[tb][tid >> 6] = ss1; }
  }
  __syncthreads();

  float inv[G_];
#pragma unroll
  for (int tok = 0; tok < G_; tok++)
    inv[tok] = rsqrtf((red[tok][0] + red[tok][1] + red[tok][2] + red[tok][3]) * (1.0f / D_) + EPS_);

  // ---- stage B: perceptron, 2 p per thread; one b32 read serves a token pair ----
#pragma unroll
  for (int j = 0; j < 2; j++) {
    int p = tid + j * 256;
    union { int4 v[4]; int s[16]; } iu;
    const int4* ip = reinterpret_cast<const int4*>(idx + p * K_);
    iu.v[0] = ip[0]; iu.v[1] = ip[1]; iu.v[2] = ip[2]; iu.v[3] = ip[3];
    union { float4 v[4]; float s[16]; } wu;
    const float4* wp = reinterpret_cast<const float4*>(wg + p * K_);
    wu.v[0] = wp[0]; wu.v[1] = wp[1]; wu.v[2] = wp[2]; wu.v[3] = wp[3];
    float wqp = wq[p];
#pragma unroll
    for (int pr = 0; pr < 2; pr++) {
      int ta = 2 * pr, tb = ta + 1;
      float a0 = 0, a1 = 0;
#pragma unroll
      for (int k = 0; k < K_; k++) {
        u32 w = h1p[pr][iu.s[k]];
        a0 += bflo(w) * wu.s[k];
        a1 += bfhi(w) * wu.s[k];
      }
      float u0 = wqp * inv[ta] * a0, u1 = wqp * inv[tb] * a1;
      float f0 = sigmoidf_(u0), f1 = sigmoidf_(u1);
      tf[ta][p] = packbf(f0 * u0, f0);   // lo=t, hi=f
      tf[tb][p] = packbf(f1 * u1, f1);
      f_ssm[(size_t)(token0 + ta) * P_ + p] = f2bfb(f0);
      f_ssm[(size_t)(token0 + tb) * P_ + p] = f2bfb(f1);
    }
  }
  __syncthreads();

  // ---- stage C: z = t@U, lam = sigmoid(f@Wgt + b); uint4 broadcast reads ----
  int r = tid & 31, g = tid >> 5;  // 32 r x 8 p-groups of 64
  float zs[G_], ls[G_];
#pragma unroll
  for (int tok = 0; tok < G_; tok++) { zs[tok] = 0; ls[tok] = 0; }
  int pb = g * 64;
#pragma unroll 2
  for (int pq = 0; pq < 16; pq++) {
    int p = pb + pq * 4;
    float u0 = U[(p + 0) * R_ + r], u1 = U[(p + 1) * R_ + r];
    float u2 = U[(p + 2) * R_ + r], u3 = U[(p + 3) * R_ + r];
    float w0 = Wgt[(p + 0) * R_ + r], w1 = Wgt[(p + 1) * R_ + r];
    float w2 = Wgt[(p + 2) * R_ + r], w3 = Wgt[(p + 3) * R_ + r];
#pragma unroll
    for (int tok = 0; tok < G_; tok++) {
      uint4 q = *reinterpret_cast<const uint4*>(&tf[tok][p]);
      zs[tok] += bflo(q.x) * u0 + bflo(q.y) * u1 + bflo(q.z) * u2 + bflo(q.w) * u3;
      ls[tok] += bfhi(q.x) * w0 + bfhi(q.y) * w1 + bfhi(q.z) * w2 + bfhi(q.w) * w3;
    }
  }
#pragma unroll
  for (int tok = 0; tok < G_; tok++) {
    zs[tok] += __shfl_down(zs[tok], 32);
    ls[tok] += __shfl_down(ls[tok], 32);
  }
  int wid = tid >> 6;
  if ((tid & 63) < 32) {
#pragma unroll
    for (int tok = 0; tok < G_; tok++) { zp[tok][r][wid] = zs[tok]; lp[tok][r][wid] = ls[tok]; }
  }
  __syncthreads();
  if (tid < R_) {
    float bgr = bg[tid];
    float z4[G_], l4[G_];
#pragma unroll
    for (int tok = 0; tok < G_; tok++) {
      float zz = zp[tok][tid][0] + zp[tok][tid][1] + zp[tok][tid][2] + zp[tok][tid][3];
      float ll = lp[tok][tid][0] + lp[tok][tid][1] + lp[tok][tid][2] + lp[tok][tid][3];
      z4[tok] = zz;
      l4[tok] = sigmoidf_(ll + bgr);
    }
    size_t o = ((size_t)(b * R_ + tid)) * T_ + t0;
    *reinterpret_cast<float4*>(&z[o]) = *reinterpret_cast<const float4*>(z4);
    *reinterpret_cast<float4*>(&lam[o]) = *reinterpret_cast<const float4*>(l4);
  }
}

// ---------------- K2: parallel linear scan over T (one wave per (b,r)) ----------------
__global__ __launch_bounds__(64) void k_scan(
    const float* __restrict__ z, const float* __restrict__ lam,
    const float* __restrict__ state, float* __restrict__ S,
    float* __restrict__ out_state) {
  int br = blockIdx.x;     // b*R + r   (128 total)
  int lane = threadIdx.x;  // 64 lanes, 32 timesteps each
  const float* zr = z + (size_t)br * T_ + lane * 32;
  const float* lr = lam + (size_t)br * T_ + lane * 32;
  float zb[32], lb[32];
#pragma unroll
  for (int i = 0; i < 32; i += 4) {
    *reinterpret_cast<float4*>(&zb[i]) = *reinterpret_cast<const float4*>(&zr[i]);
    *reinterpret_cast<float4*>(&lb[i]) = *reinterpret_cast<const float4*>(&lr[i]);
  }
  float A = 1.0f, Z = 0.0f;
#pragma unroll
  for (int i = 0; i < 32; i++) { Z = lb[i] * Z + zb[i]; A *= lb[i]; }
  for (int off = 1; off < 64; off <<= 1) {
    float Ap = __shfl_up(A, off);
    float Zp = __shfl_up(Z, off);
    if (lane >= off) { Z = A * Zp + Z; A = A * Ap; }
  }
  float s0 = state[br];
  float Ae = __shfl_up(A, 1);
  float Ze = __shfl_up(Z, 1);
  float s = (lane == 0) ? s0 : (Ae * s0 + Ze);
  float sb[32];
#pragma unroll
  for (int i = 0; i < 32; i++) { s = lb[i] * s + zb[i]; sb[i] = s; }
  float* Sr = S + (size_t)br * T_ + lane * 32;
#pragma unroll
  for (int i = 0; i < 32; i += 4)
    *reinterpret_cast<float4*>(&Sr[i]) = *reinterpret_cast<const float4*>(&sb[i]);
  if (lane == 63) out_state[br] = s;  // new_state
}

// ---------------- K3: tilde=S@V, y_ssm, x_after, rmsnorm2, MLP, out ----------------
// Pair-packed h2 (same trick): MLP gather DS ops halve (128 u16 -> 64 b32).
__global__ __launch_bounds__(256) void k_phase3(
    const float* __restrict__ x, const float* __restrict__ g2,
    const int* __restrict__ idx, const float* __restrict__ wg,
    const float* __restrict__ V, const float* __restrict__ S,
    const u16* __restrict__ f_ssm, const float* __restrict__ fo_s,
    const float* __restrict__ wq_m, const float* __restrict__ fo_m,
    float* __restrict__ out) {
  __shared__ float Sl[G_][R_];
  __shared__ u32 h2p[2][D_];        // 16 KB  pair-packed bf16(xa*g2), inv deferred
  __shared__ float red[G_][4];

  int tid = threadIdx.x;
  int token0 = blockIdx.x * G_;
  int b = token0 >> 11;
  int t0 = token0 & (T_ - 1);
  int p0 = 2 * tid;

  if (tid < G_ * R_) {
    int tok = tid >> 5, r = tid & 31;
    Sl[tok][r] = S[((size_t)(b * R_ + r)) * T_ + t0 + tok];
  }
  __syncthreads();

  // ---- tilde = S @ V (scalar Sl broadcasts, low VGPR) ----
  float til0[G_], til1[G_];
#pragma unroll
  for (int tok = 0; tok < G_; tok++) { til0[tok] = 0; til1[tok] = 0; }
#pragma unroll 4
  for (int r = 0; r < R_; r++) {
    float2 vv = *reinterpret_cast<const float2*>(V + r * P_ + p0);
#pragma unroll
    for (int tok = 0; tok < G_; tok++) {
      float s = Sl[tok][r];
      til0[tok] += s * vv.x;
      til1[tok] += s * vv.y;
    }
  }

  float2 fo = *reinterpret_cast<const float2*>(fo_s + p0);
  float gv[8];
  {
    const float4* gp = reinterpret_cast<const float4*>(g2 + tid * 8);
    *reinterpret_cast<float4*>(&gv[0]) = gp[0];
    *reinterpret_cast<float4*>(&gv[4]) = gp[1];
  }

  // ---- xa = x + y_ssm; ss partials; pair-packed h2 write ----
  float xa[G_][8];
#pragma unroll
  for (int pr = 0; pr < 2; pr++) {
    int ta = 2 * pr, tb = ta + 1;
#pragma unroll
    for (int h = 0; h < 2; h++) {
      int tok = ta + h;
      u32 ff = *reinterpret_cast<const u32*>(f_ssm + (size_t)(token0 + tok) * P_ + p0);
      float val0 = bflo(ff) * (h ? til0[tb] : til0[ta]) * fo.x;
      float val1 = bfhi(ff) * (h ? til1[tb] : til1[ta]) * fo.y;
      float xv[8];
      const float4* xp = reinterpret_cast<const float4*>(x + (size_t)(token0 + tok) * D_ + tid * 8);
      *reinterpret_cast<float4*>(&xv[0]) = xp[0];
      *reinterpret_cast<float4*>(&xv[4]) = xp[1];
      float ss = 0;
#pragma unroll
      for (int a = 0; a < 4; a++) {
        float v0 = xv[a] + val0;
        float v1 = xv[4 + a] + val1;
        xa[tok][a] = v0;
        xa[tok][4 + a] = v1;
        ss += v0 * v0 + v1 * v1;
      }
#pragma unroll
      for (int off = 32; off; off >>= 1) ss += __shfl_down(ss, off);
      if ((tid & 63) == 0) red[tok][tid >> 6] = ss;
    }
    u32 tmp[8];
#pragma unroll
    for (int i = 0; i < 8; i++)
      tmp[i] = packbf(xa[ta][i] * gv[i], xa[tb][i] * gv[i]);
    uint4* hp = reinterpret_cast<uint4*>(&h2p[pr][tid * 8]);
    hp[0] = *reinterpret_cast<const uint4*>(&tmp[0]);
    hp[1] = *reinterpret_cast<const uint4*>(&tmp[4]);
  }
  __syncthreads();

  // ---- MLP gather: weights loaded here (short live range); pair reads ----
  union { int4 v[4]; int s[16]; } iu0, iu1;
  union { float4 v[4]; float s[16]; } wu0, wu1;
  {
    const int4* ip0 = reinterpret_cast<const int4*>(idx + p0 * K_);
    const int4* ip1 = reinterpret_cast<const int4*>(idx + (p0 + 1) * K_);
    const float4* wp0 = reinterpret_cast<const float4*>(wg + p0 * K_);
    const float4* wp1 = reinterpret_cast<const float4*>(wg + (p0 + 1) * K_);
#pragma unroll
    for (int q = 0; q < 4; q++) { iu0.v[q] = ip0[q]; iu1.v[q] = ip1[q]; wu0.v[q] = wp0[q]; wu1.v[q] = wp1[q]; }
  }
  float2 wqm = *reinterpret_cast<const float2*>(wq_m + p0);
  float2 fom = *reinterpret_cast<const float2*>(fo_m + p0);

#pragma unroll
  for (int pr = 0; pr < 2; pr++) {
    float a00 = 0, a01 = 0, a10 = 0, a11 = 0;  // a{neuron}{tokInPair}
#pragma unroll
    for (int k = 0; k < K_; k++) {
      u32 w0 = h2p[pr][iu0.s[k]];
      u32 w1 = h2p[pr][iu1.s[k]];
      a00 += bflo(w0) * wu0.s[k];
      a01 += bfhi(w0) * wu0.s[k];
      a10 += bflo(w1) * wu1.s[k];
      a11 += bfhi(w1) * wu1.s[k];
    }
#pragma unroll
    for (int h = 0; h < 2; h++) {
      int tok = 2 * pr + h;
      float invt = rsqrtf((red[tok][0] + red[tok][1] + red[tok][2] + red[tok][3]) * (1.0f / D_) + EPS_);
      float accA = h ? a01 : a00;
      float accB = h ? a11 : a10;
      float u0 = wqm.x * invt * accA, u1 = wqm.y * invt * accB;
      float f0 = sigmoidf_(u0), f1 = sigmoidf_(u1);
      float val0 = f0 * u0 * fom.x, val1 = f1 * u1 * fom.y;
      float ov[8];
#pragma unroll
      for (int a = 0; a < 4; a++) {
        ov[a] = xa[tok][a] + val0;
        ov[4 + a] = xa[tok][4 + a] + val1;
      }
      float4* op = reinterpret_cast<float4*>(out + (size_t)(token0 + tok) * D_ + tid * 8);
      op[0] = *reinterpret_cast<const float4*>(&ov[0]);
      op[1] = *reinterpret_cast<const float4*>(&ov[4]);
    }
  }
}

// ---------------- host ----------------
extern "C" void kernel_launch(void* const* d_in, const int* in_sizes, int n_in,
                              void* d_out, int out_size, void* d_ws, size_t ws_size,
                              hipStream_t stream) {
  const float* x     = (const float*)d_in[0];
  const float* state = (const float*)d_in[1];
  const float* g1    = (const float*)d_in[2];
  const float* g2    = (const float*)d_in[3];
  const int*   idx_s = (const int*)d_in[4];
  const float* wg_s  = (const float*)d_in[5];
  const int*   idx_m = (const int*)d_in[6];
  const float* wg_m  = (const float*)d_in[7];
  const float* Wp_s  = (const float*)d_in[8];
  const float* Wo_s  = (const float*)d_in[9];
  const float* Wp_m  = (const float*)d_in[10];
  const float* Wo_m  = (const float*)d_in[11];
  const float* U     = (const float*)d_in[12];
  const float* V     = (const float*)d_in[13];
  const float* Wgt   = (const float*)d_in[14];
  const float* bg    = (const float*)d_in[15];
  float* out = (float*)d_out;

  char* ws = (char*)d_ws;
  float* wq_s = (float*)(ws + 0);
  float* fo_s = (float*)(ws + 2048);
  float* wq_m = (float*)(ws + 4096);
  float* fo_m = (float*)(ws + 6144);
  u16* f_ssm = (u16*)(ws + 8192);                                    // B*T*P bf16 = 8 MB
  size_t off = 8192 + (size_t)B_ * T_ * P_ * 2;
  float* z   = (float*)(ws + off); off += (size_t)B_ * R_ * T_ * 4;  // 1 MB
  float* lam = (float*)(ws + off); off += (size_t)B_ * R_ * T_ * 4;  // 1 MB
  float* S   = (float*)(ws + off);                                   // 1 MB

  hipLaunchKernelGGL(k_scalars, dim3(2), dim3(256), 0, stream,
                     Wp_s, Wo_s, Wp_m, Wo_m, wq_s, fo_s, wq_m, fo_m);
  hipLaunchKernelGGL(k_phase1, dim3(B_ * T_ / G_), dim3(256), 0, stream,
                     x, g1, idx_s, wg_s, U, Wgt, bg, wq_s, f_ssm, z, lam);
  hipLaunchKernelGGL(k_scan, dim3(B_ * R_), dim3(64), 0, stream,
                     z, lam, state, S, out + (size_t)B_ * T_ * D_);
  hipLaunchKernelGGL(k_phase3, dim3(B_ * T_ / G_), dim3(256), 0, stream,
                     x, g2, idx_m, wg_m, V, S, f_ssm, fo_s, wq_m, fo_m, out);
}

// Round 8
// 208.072 us; speedup vs baseline: 2.8109x; 1.0017x over previous
//
#include <hip/hip_runtime.h>
#include <hip/hip_bf16.h>

// Problem constants (CeptaBlock): B=4,T=2048,D=2048,P=512,K=16,ALPHA=4,R=32
#define B_ 4
#define T_ 2048
#define D_ 2048
#define P_ 512
#define K_ 16
#define ALPHA_ 4
#define R_ 32
#define NE_ 409        // int(0.8*512) -> excitatory count
#define EPS_ 1e-6f
#define G_ 4           // tokens per block

typedef unsigned short u16;
typedef unsigned int u32;
typedef _Float16 h2t __attribute__((ext_vector_type(2)));

__device__ __forceinline__ float sigmoidf_(float x) {
  return 1.0f / (1.0f + __expf(-x));
}
__device__ __forceinline__ u16 f2bfb(float f) {
  __hip_bfloat16 h = __float2bfloat16(f);
  return *reinterpret_cast<u16*>(&h);
}
// packed-u32 (2x bf16) helpers: lo16 -> float, hi16 -> float
__device__ __forceinline__ float bflo(u32 u) { return __uint_as_float(u << 16); }
__device__ __forceinline__ float bfhi(u32 u) { return __uint_as_float(u & 0xFFFF0000u); }
__device__ __forceinline__ u32 packbf(float lo, float hi) {
  return ((u32)f2bfb(hi) << 16) | (u32)f2bfb(lo);
}
// f16 pair pack (v_cvt_pkrtz_f16_f32: 1 instruction) and weight duplication
__device__ __forceinline__ u32 packh(float lo, float hi) {
#if __has_builtin(__builtin_amdgcn_cvt_pkrtz)
  return __builtin_bit_cast(u32, __builtin_amdgcn_cvt_pkrtz(lo, hi));
#else
  union { _Float16 h; u16 u; } a, b;
  a.h = (_Float16)lo; b.h = (_Float16)hi;
  return ((u32)b.u << 16) | a.u;
#endif
}
__device__ __forceinline__ u32 duph(float w) {
  union { _Float16 h; u16 u; } c;
  c.h = (_Float16)w;
  return ((u32)c.u << 16) | c.u;
}
// packed f16 fma: acc += h * w (both lanes) -> v_pk_fma_f16
__device__ __forceinline__ h2t pkfma(u32 h, u32 w, h2t acc) {
  return __builtin_bit_cast(h2t, h) * __builtin_bit_cast(h2t, w) + acc;
}

// ---------------- K0: per-neuron quant-dale scalars ----------------
__global__ void k_scalars(const float* __restrict__ Wp_s, const float* __restrict__ Wo_s,
                          const float* __restrict__ Wp_m, const float* __restrict__ Wo_m,
                          float* __restrict__ wq_s, float* __restrict__ fo_s,
                          float* __restrict__ wq_m, float* __restrict__ fo_m) {
  int p = blockIdx.x * blockDim.x + threadIdx.x;
  if (p >= P_) return;
  float sgn = (p < NE_) ? 1.0f : -1.0f;
  float a = 0, b = 0, c = 0, d = 0;
#pragma unroll
  for (int k = 0; k < K_; k++) {
    a += fabsf(Wp_s[p * K_ + k]);
    c += fabsf(Wp_m[p * K_ + k]);
  }
#pragma unroll
  for (int k = 0; k < ALPHA_; k++) {
    b += fabsf(Wo_s[p * ALPHA_ + k]);
    d += fabsf(Wo_m[p * ALPHA_ + k]);
  }
  wq_s[p] = sgn * a * (1.0f / K_);
  fo_s[p] = sgn * b * (1.0f / ALPHA_);
  wq_m[p] = sgn * c * (1.0f / K_);
  fo_m[p] = sgn * d * (1.0f / ALPHA_);
}

// ---------------- K1: rmsnorm1 + gather + perceptron + z/lam, G_ tokens/block ----------------
// Token-PAIR-packed f16 h1: h1p[pair][d] = f16x2(h_tokA, h_tokB).
// Gather inner op = 1 ds_read_b32 + 1 v_pk_fma_f16 (both tokens at once).
// zp/lp alias h1p's LDS (dead after stage B) -> 24.1 KB -> 6 blocks/CU.
__global__ __launch_bounds__(256) void k_phase1(
    const float* __restrict__ x, const float* __restrict__ g1,
    const int* __restrict__ idx, const float* __restrict__ wg,
    const float* __restrict__ U, const float* __restrict__ Wgt,
    const float* __restrict__ bg, const float* __restrict__ wq,
    u16* __restrict__ f_ssm, float* __restrict__ z, float* __restrict__ lam) {
  __shared__ union SU {
    u32 h1p[2][D_];                                            // 16 KB (stages A,B)
    struct { float zp[G_][R_][4]; float lp[G_][R_][4]; } c;    // 4 KB (stage C)
  } su;
  __shared__ u32 tf[G_][P_];        // 8 KB   packed (f<<16)|t  bf16x2
  __shared__ float red[G_][4];

  int tid = threadIdx.x;
  int token0 = blockIdx.x * G_;
  int b = token0 >> 11;
  int t0 = token0 & (T_ - 1);

  // ---- stage A: load x for token pairs, write packed f16 h1 + ss partials ----
  float gv[8];
  {
    const float4* gp = reinterpret_cast<const float4*>(g1 + tid * 8);
    *reinterpret_cast<float4*>(&gv[0]) = gp[0];
    *reinterpret_cast<float4*>(&gv[4]) = gp[1];
  }
#pragma unroll
  for (int pr = 0; pr < 2; pr++) {
    int ta = 2 * pr, tb = ta + 1;
    float xv0[8], xv1[8];
    const float4* xp0 = reinterpret_cast<const float4*>(x + (size_t)(token0 + ta) * D_ + tid * 8);
    const float4* xp1 = reinterpret_cast<const float4*>(x + (size_t)(token0 + tb) * D_ + tid * 8);
    *reinterpret_cast<float4*>(&xv0[0]) = xp0[0];
    *reinterpret_cast<float4*>(&xv0[4]) = xp0[1];
    *reinterpret_cast<float4*>(&xv1[0]) = xp1[0];
    *reinterpret_cast<float4*>(&xv1[4]) = xp1[1];
    float ss0 = 0, ss1 = 0;
    u32 tmp[8];
#pragma unroll
    for (int i = 0; i < 8; i++) {
      ss0 += xv0[i] * xv0[i];
      ss1 += xv1[i] * xv1[i];
      tmp[i] = packh(xv0[i] * gv[i], xv1[i] * gv[i]);
    }
    uint4* hp = reinterpret_cast<uint4*>(&su.h1p[pr][tid * 8]);
    hp[0] = *reinterpret_cast<const uint4*>(&tmp[0]);
    hp[1] = *reinterpret_cast<const uint4*>(&tmp[4]);
#pragma unroll
    for (int off = 32; off; off >>= 1) {
      ss0 += __shfl_down(ss0, off);
      ss1 += __shfl_down(ss1, off);
    }
    if ((tid & 63) == 0) { red[ta][tid >> 6] = ss0; red[tb][tid >> 6] = ss1; }
  }
  __syncthreads();

  float inv[G_];
#pragma unroll
  for (int tok = 0; tok < G_; tok++)
    inv[tok] = rsqrtf((red[tok][0] + red[tok][1] + red[tok][2] + red[tok][3]) * (1.0f / D_) + EPS_);

  // ---- stage B: perceptron, 2 p per thread; 1 pk_fma per gathered word ----
#pragma unroll
  for (int j = 0; j < 2; j++) {
    int p = tid + j * 256;
    union { int4 v[4]; int s[16]; } iu;
    const int4* ip = reinterpret_cast<const int4*>(idx + p * K_);
    iu.v[0] = ip[0]; iu.v[1] = ip[1]; iu.v[2] = ip[2]; iu.v[3] = ip[3];
    u32 wd[16];  // f16x2-duplicated gather weights
    {
      const float4* wp = reinterpret_cast<const float4*>(wg + p * K_);
#pragma unroll
      for (int q = 0; q < 4; q++) {
        float4 w = wp[q];
        wd[4 * q + 0] = duph(w.x);
        wd[4 * q + 1] = duph(w.y);
        wd[4 * q + 2] = duph(w.z);
        wd[4 * q + 3] = duph(w.w);
      }
    }
    float wqp = wq[p];
#pragma unroll
    for (int pr = 0; pr < 2; pr++) {
      int ta = 2 * pr, tb = ta + 1;
      h2t acc = {(_Float16)0.0f, (_Float16)0.0f};
#pragma unroll
      for (int k = 0; k < K_; k++) acc = pkfma(su.h1p[pr][iu.s[k]], wd[k], acc);
      float a0 = (float)acc.x, a1 = (float)acc.y;
      float u0 = wqp * inv[ta] * a0, u1 = wqp * inv[tb] * a1;
      float f0 = sigmoidf_(u0), f1 = sigmoidf_(u1);
      tf[ta][p] = packbf(f0 * u0, f0);   // lo=t, hi=f (bf16, proven stage-C form)
      tf[tb][p] = packbf(f1 * u1, f1);
      f_ssm[(size_t)(token0 + ta) * P_ + p] = f2bfb(f0);
      f_ssm[(size_t)(token0 + tb) * P_ + p] = f2bfb(f1);
    }
  }
  __syncthreads();

  // ---- stage C: z = t@U, lam = sigmoid(f@Wgt + b); uint4 broadcast reads ----
  int r = tid & 31, g = tid >> 5;  // 32 r x 8 p-groups of 64
  float zs[G_], ls[G_];
#pragma unroll
  for (int tok = 0; tok < G_; tok++) { zs[tok] = 0; ls[tok] = 0; }
  int pb = g * 64;
#pragma unroll 2
  for (int pq = 0; pq < 16; pq++) {
    int p = pb + pq * 4;
    float u0 = U[(p + 0) * R_ + r], u1 = U[(p + 1) * R_ + r];
    float u2 = U[(p + 2) * R_ + r], u3 = U[(p + 3) * R_ + r];
    float w0 = Wgt[(p + 0) * R_ + r], w1 = Wgt[(p + 1) * R_ + r];
    float w2 = Wgt[(p + 2) * R_ + r], w3 = Wgt[(p + 3) * R_ + r];
#pragma unroll
    for (int tok = 0; tok < G_; tok++) {
      uint4 q = *reinterpret_cast<const uint4*>(&tf[tok][p]);
      zs[tok] += bflo(q.x) * u0 + bflo(q.y) * u1 + bflo(q.z) * u2 + bflo(q.w) * u3;
      ls[tok] += bfhi(q.x) * w0 + bfhi(q.y) * w1 + bfhi(q.z) * w2 + bfhi(q.w) * w3;
    }
  }
#pragma unroll
  for (int tok = 0; tok < G_; tok++) {
    zs[tok] += __shfl_down(zs[tok], 32);
    ls[tok] += __shfl_down(ls[tok], 32);
  }
  int wid = tid >> 6;
  if ((tid & 63) < 32) {
#pragma unroll
    for (int tok = 0; tok < G_; tok++) { su.c.zp[tok][r][wid] = zs[tok]; su.c.lp[tok][r][wid] = ls[tok]; }
  }
  __syncthreads();
  if (tid < R_) {
    float bgr = bg[tid];
    float z4[G_], l4[G_];
#pragma unroll
    for (int tok = 0; tok < G_; tok++) {
      float zz = su.c.zp[tok][tid][0] + su.c.zp[tok][tid][1] + su.c.zp[tok][tid][2] + su.c.zp[tok][tid][3];
      float ll = su.c.lp[tok][tid][0] + su.c.lp[tok][tid][1] + su.c.lp[tok][tid][2] + su.c.lp[tok][tid][3];
      z4[tok] = zz;
      l4[tok] = sigmoidf_(ll + bgr);
    }
    size_t o = ((size_t)(b * R_ + tid)) * T_ + t0;
    *reinterpret_cast<float4*>(&z[o]) = *reinterpret_cast<const float4*>(z4);
    *reinterpret_cast<float4*>(&lam[o]) = *reinterpret_cast<const float4*>(l4);
  }
}

// ---------------- K2: parallel linear scan over T (one wave per (b,r)) ----------------
__global__ __launch_bounds__(64) void k_scan(
    const float* __restrict__ z, const float* __restrict__ lam,
    const float* __restrict__ state, float* __restrict__ S,
    float* __restrict__ out_state) {
  int br = blockIdx.x;     // b*R + r   (128 total)
  int lane = threadIdx.x;  // 64 lanes, 32 timesteps each
  const float* zr = z + (size_t)br * T_ + lane * 32;
  const float* lr = lam + (size_t)br * T_ + lane * 32;
  float zb[32], lb[32];
#pragma unroll
  for (int i = 0; i < 32; i += 4) {
    *reinterpret_cast<float4*>(&zb[i]) = *reinterpret_cast<const float4*>(&zr[i]);
    *reinterpret_cast<float4*>(&lb[i]) = *reinterpret_cast<const float4*>(&lr[i]);
  }
  float A = 1.0f, Z = 0.0f;
#pragma unroll
  for (int i = 0; i < 32; i++) { Z = lb[i] * Z + zb[i]; A *= lb[i]; }
  for (int off = 1; off < 64; off <<= 1) {
    float Ap = __shfl_up(A, off);
    float Zp = __shfl_up(Z, off);
    if (lane >= off) { Z = A * Zp + Z; A = A * Ap; }
  }
  float s0 = state[br];
  float Ae = __shfl_up(A, 1);
  float Ze = __shfl_up(Z, 1);
  float s = (lane == 0) ? s0 : (Ae * s0 + Ze);
  float sb[32];
#pragma unroll
  for (int i = 0; i < 32; i++) { s = lb[i] * s + zb[i]; sb[i] = s; }
  float* Sr = S + (size_t)br * T_ + lane * 32;
#pragma unroll
  for (int i = 0; i < 32; i += 4)
    *reinterpret_cast<float4*>(&Sr[i]) = *reinterpret_cast<const float4*>(&sb[i]);
  if (lane == 63) out_state[br] = s;  // new_state
}

// ---------------- K3: tilde=S@V, y_ssm, x_after, rmsnorm2, MLP, out ----------------
// Pair-packed f16 h2 + pk_fma gather (1 ds_read + 1 pk_fma per word per neuron).
__global__ __launch_bounds__(256) void k_phase3(
    const float* __restrict__ x, const float* __restrict__ g2,
    const int* __restrict__ idx, const float* __restrict__ wg,
    const float* __restrict__ V, const float* __restrict__ S,
    const u16* __restrict__ f_ssm, const float* __restrict__ fo_s,
    const float* __restrict__ wq_m, const float* __restrict__ fo_m,
    float* __restrict__ out) {
  __shared__ float Sl[G_][R_];
  __shared__ u32 h2p[2][D_];        // 16 KB  pair-packed f16(xa*g2), inv deferred
  __shared__ float red[G_][4];

  int tid = threadIdx.x;
  int token0 = blockIdx.x * G_;
  int b = token0 >> 11;
  int t0 = token0 & (T_ - 1);
  int p0 = 2 * tid;

  if (tid < G_ * R_) {
    int tok = tid >> 5, r = tid & 31;
    Sl[tok][r] = S[((size_t)(b * R_ + r)) * T_ + t0 + tok];
  }
  __syncthreads();

  // ---- tilde = S @ V (scalar Sl broadcasts, low VGPR) ----
  float til0[G_], til1[G_];
#pragma unroll
  for (int tok = 0; tok < G_; tok++) { til0[tok] = 0; til1[tok] = 0; }
#pragma unroll 4
  for (int r = 0; r < R_; r++) {
    float2 vv = *reinterpret_cast<const float2*>(V + r * P_ + p0);
#pragma unroll
    for (int tok = 0; tok < G_; tok++) {
      float s = Sl[tok][r];
      til0[tok] += s * vv.x;
      til1[tok] += s * vv.y;
    }
  }

  float2 fo = *reinterpret_cast<const float2*>(fo_s + p0);
  float gv[8];
  {
    const float4* gp = reinterpret_cast<const float4*>(g2 + tid * 8);
    *reinterpret_cast<float4*>(&gv[0]) = gp[0];
    *reinterpret_cast<float4*>(&gv[4]) = gp[1];
  }

  // ---- xa = x + y_ssm; ss partials; pair-packed f16 h2 write ----
  float xa[G_][8];
#pragma unroll
  for (int pr = 0; pr < 2; pr++) {
    int ta = 2 * pr, tb = ta + 1;
#pragma unroll
    for (int h = 0; h < 2; h++) {
      int tok = ta + h;
      u32 ff = *reinterpret_cast<const u32*>(f_ssm + (size_t)(token0 + tok) * P_ + p0);
      float val0 = bflo(ff) * (h ? til0[tb] : til0[ta]) * fo.x;
      float val1 = bfhi(ff) * (h ? til1[tb] : til1[ta]) * fo.y;
      float xv[8];
      const float4* xp = reinterpret_cast<const float4*>(x + (size_t)(token0 + tok) * D_ + tid * 8);
      *reinterpret_cast<float4*>(&xv[0]) = xp[0];
      *reinterpret_cast<float4*>(&xv[4]) = xp[1];
      float ss = 0;
#pragma unroll
      for (int a = 0; a < 4; a++) {
        float v0 = xv[a] + val0;
        float v1 = xv[4 + a] + val1;
        xa[tok][a] = v0;
        xa[tok][4 + a] = v1;
        ss += v0 * v0 + v1 * v1;
      }
#pragma unroll
      for (int off = 32; off; off >>= 1) ss += __shfl_down(ss, off);
      if ((tid & 63) == 0) red[tok][tid >> 6] = ss;
    }
    u32 tmp[8];
#pragma unroll
    for (int i = 0; i < 8; i++)
      tmp[i] = packh(xa[ta][i] * gv[i], xa[tb][i] * gv[i]);
    uint4* hp = reinterpret_cast<uint4*>(&h2p[pr][tid * 8]);
    hp[0] = *reinterpret_cast<const uint4*>(&tmp[0]);
    hp[1] = *reinterpret_cast<const uint4*>(&tmp[4]);
  }
  __syncthreads();

  // ---- MLP gather: f16x2-dup weights, pk_fma accumulation ----
  union { int4 v[4]; int s[16]; } iu0, iu1;
  u32 wd0[16], wd1[16];
  {
    const int4* ip0 = reinterpret_cast<const int4*>(idx + p0 * K_);
    const int4* ip1 = reinterpret_cast<const int4*>(idx + (p0 + 1) * K_);
#pragma unroll
    for (int q = 0; q < 4; q++) { iu0.v[q] = ip0[q]; iu1.v[q] = ip1[q]; }
    const float4* wp0 = reinterpret_cast<const float4*>(wg + p0 * K_);
    const float4* wp1 = reinterpret_cast<const float4*>(wg + (p0 + 1) * K_);
#pragma unroll
    for (int q = 0; q < 4; q++) {
      float4 w0 = wp0[q], w1 = wp1[q];
      wd0[4 * q + 0] = duph(w0.x); wd0[4 * q + 1] = duph(w0.y);
      wd0[4 * q + 2] = duph(w0.z); wd0[4 * q + 3] = duph(w0.w);
      wd1[4 * q + 0] = duph(w1.x); wd1[4 * q + 1] = duph(w1.y);
      wd1[4 * q + 2] = duph(w1.z); wd1[4 * q + 3] = duph(w1.w);
    }
  }
  float2 wqm = *reinterpret_cast<const float2*>(wq_m + p0);
  float2 fom = *reinterpret_cast<const float2*>(fo_m + p0);

#pragma unroll
  for (int pr = 0; pr < 2; pr++) {
    h2t acc0 = {(_Float16)0.0f, (_Float16)0.0f};
    h2t acc1 = {(_Float16)0.0f, (_Float16)0.0f};
#pragma unroll
    for (int k = 0; k < K_; k++) {
      acc0 = pkfma(h2p[pr][iu0.s[k]], wd0[k], acc0);
      acc1 = pkfma(h2p[pr][iu1.s[k]], wd1[k], acc1);
    }
    float a00 = (float)acc0.x, a01 = (float)acc0.y;  // neuron p0: tokA, tokB
    float a10 = (float)acc1.x, a11 = (float)acc1.y;  // neuron p1: tokA, tokB
#pragma unroll
    for (int h = 0; h < 2; h++) {
      int tok = 2 * pr + h;
      float invt = rsqrtf((red[tok][0] + red[tok][1] + red[tok][2] + red[tok][3]) * (1.0f / D_) + EPS_);
      float accA = h ? a01 : a00;
      float accB = h ? a11 : a10;
      float u0 = wqm.x * invt * accA, u1 = wqm.y * invt * accB;
      float f0 = sigmoidf_(u0), f1 = sigmoidf_(u1);
      float val0 = f0 * u0 * fom.x, val1 = f1 * u1 * fom.y;
      float ov[8];
#pragma unroll
      for (int a = 0; a < 4; a++) {
        ov[a] = xa[tok][a] + val0;
        ov[4 + a] = xa[tok][4 + a] + val1;
      }
      float4* op = reinterpret_cast<float4*>(out + (size_t)(token0 + tok) * D_ + tid * 8);
      op[0] = *reinterpret_cast<const float4*>(&ov[0]);
      op[1] = *reinterpret_cast<const float4*>(&ov[4]);
    }
  }
}

// ---------------- host ----------------
extern "C" void kernel_launch(void* const* d_in, const int* in_sizes, int n_in,
                              void* d_out, int out_size, void* d_ws, size_t ws_size,
                              hipStream_t stream) {
  const float* x     = (const float*)d_in[0];
  const float* state = (const float*)d_in[1];
  const float* g1    = (const float*)d_in[2];
  const float* g2    = (const float*)d_in[3];
  const int*   idx_s = (const int*)d_in[4];
  const float* wg_s  = (const float*)d_in[5];
  const int*   idx_m = (const int*)d_in[6];
  const float* wg_m  = (const float*)d_in[7];
  const float* Wp_s  = (const float*)d_in[8];
  const float* Wo_s  = (const float*)d_in[9];
  const float* Wp_m  = (const float*)d_in[10];
  const float* Wo_m  = (const float*)d_in[11];
  const float* U     = (const float*)d_in[12];
  const float* V     = (const float*)d_in[13];
  const float* Wgt   = (const float*)d_in[14];
  const float* bg    = (const float*)d_in[15];
  float* out = (float*)d_out;

  char* ws = (char*)d_ws;
  float* wq_s = (float*)(ws + 0);
  float* fo_s = (float*)(ws + 2048);
  float* wq_m = (float*)(ws + 4096);
  float* fo_m = (float*)(ws + 6144);
  u16* f_ssm = (u16*)(ws + 8192);                                    // B*T*P bf16 = 8 MB
  size_t off = 8192 + (size_t)B_ * T_ * P_ * 2;
  float* z   = (float*)(ws + off); off += (size_t)B_ * R_ * T_ * 4;  // 1 MB
  float* lam = (float*)(ws + off); off += (size_t)B_ * R_ * T_ * 4;  // 1 MB
  float* S   = (float*)(ws + off);                                   // 1 MB

  hipLaunchKernelGGL(k_scalars, dim3(2), dim3(256), 0, stream,
                     Wp_s, Wo_s, Wp_m, Wo_m, wq_s, fo_s, wq_m, fo_m);
  hipLaunchKernelGGL(k_phase1, dim3(B_ * T_ / G_), dim3(256), 0, stream,
                     x, g1, idx_s, wg_s, U, Wgt, bg, wq_s, f_ssm, z, lam);
  hipLaunchKernelGGL(k_scan, dim3(B_ * R_), dim3(64), 0, stream,
                     z, lam, state, S, out + (size_t)B_ * T_ * D_);
  hipLaunchKernelGGL(k_phase3, dim3(B_ * T_ / G_), dim3(256), 0, stream,
                     x, g2, idx_m, wg_m, V, S, f_ssm, fo_s, wq_m, fo_m, out);
}

// Round 9
// 207.588 us; speedup vs baseline: 2.8174x; 1.0023x over previous
//
#include <hip/hip_runtime.h>
#include <hip/hip_bf16.h>

// Problem constants (CeptaBlock): B=4,T=2048,D=2048,P=512,K=16,ALPHA=4,R=32
#define B_ 4
#define T_ 2048
#define D_ 2048
#define P_ 512
#define K_ 16
#define ALPHA_ 4
#define R_ 32
#define NE_ 409        // int(0.8*512) -> excitatory count
#define EPS_ 1e-6f
#define G_ 4           // tokens per block

typedef unsigned short u16;
typedef unsigned int u32;
typedef _Float16 h2t __attribute__((ext_vector_type(2)));

__device__ __forceinline__ float sigmoidf_(float x) {
  return 1.0f / (1.0f + __expf(-x));
}
__device__ __forceinline__ float bfb2f(u16 u) {
  return __uint_as_float(((u32)u) << 16);
}
__device__ __forceinline__ u16 f2bfb(float f) {
  __hip_bfloat16 h = __float2bfloat16(f);
  return *reinterpret_cast<u16*>(&h);
}
// f16 pair pack (v_cvt_pkrtz_f16_f32) and f16x2 weight duplication
__device__ __forceinline__ u32 packh(float lo, float hi) {
#if __has_builtin(__builtin_amdgcn_cvt_pkrtz)
  return __builtin_bit_cast(u32, __builtin_amdgcn_cvt_pkrtz(lo, hi));
#else
  union { _Float16 h; u16 u; } a, b;
  a.h = (_Float16)lo; b.h = (_Float16)hi;
  return ((u32)b.u << 16) | a.u;
#endif
}
__device__ __forceinline__ u32 duph(float w) {
  union { _Float16 h; u16 u; } c;
  c.h = (_Float16)w;
  return ((u32)c.u << 16) | c.u;
}
// packed f16 fma: acc += h * w (both lanes) -> v_pk_fma_f16
__device__ __forceinline__ h2t pkfma(u32 h, u32 w, h2t acc) {
  return __builtin_bit_cast(h2t, h) * __builtin_bit_cast(h2t, w) + acc;
}

// ---------------- K0: quant-dale scalars + f16x2-duplicated weight tables ----------------
__global__ void k_scalars(const float* __restrict__ Wp_s, const float* __restrict__ Wo_s,
                          const float* __restrict__ Wp_m, const float* __restrict__ Wo_m,
                          const float* __restrict__ U, const float* __restrict__ Wgt,
                          const float* __restrict__ wg_s, const float* __restrict__ wg_m,
                          float* __restrict__ wq_s, float* __restrict__ fo_s,
                          float* __restrict__ wq_m, float* __restrict__ fo_m,
                          u32* __restrict__ Ud, u32* __restrict__ Wd,
                          u32* __restrict__ wgd_s, u32* __restrict__ wgd_m) {
  int p = blockIdx.x * blockDim.x + threadIdx.x;
  if (p >= P_) return;
  float sgn = (p < NE_) ? 1.0f : -1.0f;
  float a = 0, b = 0, c = 0, d = 0;
#pragma unroll
  for (int k = 0; k < K_; k++) {
    a += fabsf(Wp_s[p * K_ + k]);
    c += fabsf(Wp_m[p * K_ + k]);
  }
#pragma unroll
  for (int k = 0; k < ALPHA_; k++) {
    b += fabsf(Wo_s[p * ALPHA_ + k]);
    d += fabsf(Wo_m[p * ALPHA_ + k]);
  }
  wq_s[p] = sgn * a * (1.0f / K_);
  fo_s[p] = sgn * b * (1.0f / ALPHA_);
  wq_m[p] = sgn * c * (1.0f / K_);
  fo_m[p] = sgn * d * (1.0f / ALPHA_);
#pragma unroll
  for (int r = 0; r < R_; r++) {
    Ud[p * R_ + r] = duph(U[p * R_ + r]);
    Wd[p * R_ + r] = duph(Wgt[p * R_ + r]);
  }
#pragma unroll
  for (int k = 0; k < K_; k++) {
    wgd_s[p * K_ + k] = duph(wg_s[p * K_ + k]);
    wgd_m[p * K_ + k] = duph(wg_m[p * K_ + k]);
  }
}

// ---------------- K1: 512 threads; rmsnorm1 + gather + perceptron + z/lam ----------------
// 8 waves/block -> up to 4 co-resident blocks/CU (32 waves). One neuron per thread.
// Stage C fully pk_fma_f16 over token pairs with pre-duplicated Ud/Wd tables.
__global__ __launch_bounds__(512) void k_phase1(
    const float* __restrict__ x, const float* __restrict__ g1,
    const int* __restrict__ idx, const u32* __restrict__ wgd,
    const u32* __restrict__ Ud, const u32* __restrict__ Wd,
    const float* __restrict__ bg, const float* __restrict__ wq,
    u16* __restrict__ f_ssm, float* __restrict__ z, float* __restrict__ lam) {
  __shared__ union SU {
    u32 h1p[2][D_];                                            // 16 KB (stages A,B)
    struct { float zp[G_][R_][8]; float lp[G_][R_][8]; } c;    // 8 KB (stage C)
  } su;
  __shared__ u32 tp[2][P_];        // 4 KB  f16x2 (t_tokA, t_tokB)
  __shared__ u32 fp[2][P_];        // 4 KB  f16x2 (f_tokA, f_tokB)
  __shared__ float red[G_][8];
  // ~24.3 KB -> wave-limited at 4 blocks/CU

  int tid = threadIdx.x;
  int token0 = blockIdx.x * G_;
  int b = token0 >> 11;
  int t0 = token0 & (T_ - 1);

  // ---- stage A: 4 elems/thread/token; packed f16 h1 + ss partials ----
  float gv[4];
  *reinterpret_cast<float4*>(gv) = *reinterpret_cast<const float4*>(g1 + tid * 4);
#pragma unroll
  for (int pr = 0; pr < 2; pr++) {
    int ta = 2 * pr, tb = ta + 1;
    float xv0[4], xv1[4];
    *reinterpret_cast<float4*>(xv0) =
        *reinterpret_cast<const float4*>(x + (size_t)(token0 + ta) * D_ + tid * 4);
    *reinterpret_cast<float4*>(xv1) =
        *reinterpret_cast<const float4*>(x + (size_t)(token0 + tb) * D_ + tid * 4);
    float ss0 = 0, ss1 = 0;
    u32 tmp[4];
#pragma unroll
    for (int i = 0; i < 4; i++) {
      ss0 += xv0[i] * xv0[i];
      ss1 += xv1[i] * xv1[i];
      tmp[i] = packh(xv0[i] * gv[i], xv1[i] * gv[i]);
    }
    *reinterpret_cast<uint4*>(&su.h1p[pr][tid * 4]) = *reinterpret_cast<const uint4*>(tmp);
#pragma unroll
    for (int off = 32; off; off >>= 1) {
      ss0 += __shfl_down(ss0, off);
      ss1 += __shfl_down(ss1, off);
    }
    if ((tid & 63) == 0) { red[ta][tid >> 6] = ss0; red[tb][tid >> 6] = ss1; }
  }
  __syncthreads();

  float inv[G_];
#pragma unroll
  for (int tok = 0; tok < G_; tok++) {
    float s = 0;
#pragma unroll
    for (int w = 0; w < 8; w++) s += red[tok][w];
    inv[tok] = rsqrtf(s * (1.0f / D_) + EPS_);
  }

  // ---- stage B: one neuron per thread (p = tid); pk_fma gather ----
  {
    int p = tid;
    union { int4 v[4]; int s[16]; } iu;
    const int4* ip = reinterpret_cast<const int4*>(idx + p * K_);
    iu.v[0] = ip[0]; iu.v[1] = ip[1]; iu.v[2] = ip[2]; iu.v[3] = ip[3];
    union { uint4 v[4]; u32 s[16]; } wd;
    const uint4* wp = reinterpret_cast<const uint4*>(wgd + p * K_);
    wd.v[0] = wp[0]; wd.v[1] = wp[1]; wd.v[2] = wp[2]; wd.v[3] = wp[3];
    float wqp = wq[p];
#pragma unroll
    for (int pr = 0; pr < 2; pr++) {
      int ta = 2 * pr, tb = ta + 1;
      h2t acc = {(_Float16)0.0f, (_Float16)0.0f};
#pragma unroll
      for (int k = 0; k < K_; k++) acc = pkfma(su.h1p[pr][iu.s[k]], wd.s[k], acc);
      float u0 = wqp * inv[ta] * (float)acc.x, u1 = wqp * inv[tb] * (float)acc.y;
      float f0 = sigmoidf_(u0), f1 = sigmoidf_(u1);
      tp[pr][p] = packh(f0 * u0, f1 * u1);
      fp[pr][p] = packh(f0, f1);
      f_ssm[(size_t)(token0 + ta) * P_ + p] = f2bfb(f0);
      f_ssm[(size_t)(token0 + tb) * P_ + p] = f2bfb(f1);
    }
  }
  __syncthreads();

  // ---- stage C: z = t@U, lam_pre = f@Wgt via v_pk_fma_f16 (token-pair lanes) ----
  int r = tid & 31, g = tid >> 5;  // 32 r x 16 p-groups of 32
  float zs[G_] = {0, 0, 0, 0}, ls[G_] = {0, 0, 0, 0};
  int pb = g * 32;
#pragma unroll
  for (int c = 0; c < 4; c++) {     // chunks of 8: f16 accum dumped to f32
    h2t z0 = {(_Float16)0.0f, (_Float16)0.0f}, z1 = z0, l0 = z0, l1 = z0;
#pragma unroll
    for (int i = 0; i < 8; i++) {
      int p = pb + c * 8 + i;
      u32 ud = Ud[p * R_ + r];
      u32 wdd = Wd[p * R_ + r];
      z0 = pkfma(tp[0][p], ud, z0);
      z1 = pkfma(tp[1][p], ud, z1);
      l0 = pkfma(fp[0][p], wdd, l0);
      l1 = pkfma(fp[1][p], wdd, l1);
    }
    zs[0] += (float)z0.x; zs[1] += (float)z0.y; zs[2] += (float)z1.x; zs[3] += (float)z1.y;
    ls[0] += (float)l0.x; ls[1] += (float)l0.y; ls[2] += (float)l1.x; ls[3] += (float)l1.y;
  }
#pragma unroll
  for (int tok = 0; tok < G_; tok++) {
    zs[tok] += __shfl_down(zs[tok], 32);   // combine the wave's two p-groups
    ls[tok] += __shfl_down(ls[tok], 32);
  }
  int wid = tid >> 6;
  if ((tid & 63) < 32) {
#pragma unroll
    for (int tok = 0; tok < G_; tok++) { su.c.zp[tok][r][wid] = zs[tok]; su.c.lp[tok][r][wid] = ls[tok]; }
  }
  __syncthreads();
  if (tid < R_) {
    float bgr = bg[tid];
    float z4[G_], l4[G_];
#pragma unroll
    for (int tok = 0; tok < G_; tok++) {
      float zz = 0, ll = 0;
#pragma unroll
      for (int w = 0; w < 8; w++) { zz += su.c.zp[tok][tid][w]; ll += su.c.lp[tok][tid][w]; }
      z4[tok] = zz;
      l4[tok] = sigmoidf_(ll + bgr);
    }
    size_t o = ((size_t)(b * R_ + tid)) * T_ + t0;
    *reinterpret_cast<float4*>(&z[o]) = *reinterpret_cast<const float4*>(z4);
    *reinterpret_cast<float4*>(&lam[o]) = *reinterpret_cast<const float4*>(l4);
  }
}

// ---------------- K2: parallel linear scan over T (one wave per (b,r)) ----------------
__global__ __launch_bounds__(64) void k_scan(
    const float* __restrict__ z, const float* __restrict__ lam,
    const float* __restrict__ state, float* __restrict__ S,
    float* __restrict__ out_state) {
  int br = blockIdx.x;     // b*R + r   (128 total)
  int lane = threadIdx.x;  // 64 lanes, 32 timesteps each
  const float* zr = z + (size_t)br * T_ + lane * 32;
  const float* lr = lam + (size_t)br * T_ + lane * 32;
  float zb[32], lb[32];
#pragma unroll
  for (int i = 0; i < 32; i += 4) {
    *reinterpret_cast<float4*>(&zb[i]) = *reinterpret_cast<const float4*>(&zr[i]);
    *reinterpret_cast<float4*>(&lb[i]) = *reinterpret_cast<const float4*>(&lr[i]);
  }
  float A = 1.0f, Z = 0.0f;
#pragma unroll
  for (int i = 0; i < 32; i++) { Z = lb[i] * Z + zb[i]; A *= lb[i]; }
  for (int off = 1; off < 64; off <<= 1) {
    float Ap = __shfl_up(A, off);
    float Zp = __shfl_up(Z, off);
    if (lane >= off) { Z = A * Zp + Z; A = A * Ap; }
  }
  float s0 = state[br];
  float Ae = __shfl_up(A, 1);
  float Ze = __shfl_up(Z, 1);
  float s = (lane == 0) ? s0 : (Ae * s0 + Ze);
  float sb[32];
#pragma unroll
  for (int i = 0; i < 32; i++) { s = lb[i] * s + zb[i]; sb[i] = s; }
  float* Sr = S + (size_t)br * T_ + lane * 32;
#pragma unroll
  for (int i = 0; i < 32; i += 4)
    *reinterpret_cast<float4*>(&Sr[i]) = *reinterpret_cast<const float4*>(&sb[i]);
  if (lane == 63) out_state[br] = s;  // new_state
}

// ---------------- K3: 512 threads; tilde=S@V, y_ssm, x_after, rmsnorm2, MLP, out ----------------
// One neuron per thread (p = tid) aligned with its 4 output dims (p*4..p*4+3).
__global__ __launch_bounds__(512) void k_phase3(
    const float* __restrict__ x, const float* __restrict__ g2,
    const int* __restrict__ idx, const u32* __restrict__ wgd,
    const float* __restrict__ V, const float* __restrict__ S,
    const u16* __restrict__ f_ssm, const float* __restrict__ fo_s,
    const float* __restrict__ wq_m, const float* __restrict__ fo_m,
    float* __restrict__ out) {
  __shared__ float Sl[G_][R_];      // 0.5 KB
  __shared__ u32 h2p[2][D_];        // 16 KB  pair-packed f16(xa*g2), inv deferred
  __shared__ float red[G_][8];
  // ~16.8 KB

  int tid = threadIdx.x;
  int token0 = blockIdx.x * G_;
  int b = token0 >> 11;
  int t0 = token0 & (T_ - 1);
  int p = tid;

  if (tid < G_ * R_) {
    int tok = tid >> 5, r = tid & 31;
    Sl[tok][r] = S[((size_t)(b * R_ + r)) * T_ + t0 + tok];
  }
  __syncthreads();

  // ---- tilde = S @ V: one V column per thread ----
  float til[G_] = {0, 0, 0, 0};
#pragma unroll 4
  for (int r = 0; r < R_; r++) {
    float v = V[r * P_ + p];
#pragma unroll
    for (int tok = 0; tok < G_; tok++) til[tok] += Sl[tok][r] * v;
  }

  float fo = fo_s[p];
  float gv[4];
  *reinterpret_cast<float4*>(gv) = *reinterpret_cast<const float4*>(g2 + tid * 4);

  // ---- xa = x + y_ssm; ss partials; pair-packed f16 h2 write ----
  float xa[G_][4];
#pragma unroll
  for (int pr = 0; pr < 2; pr++) {
    int ta = 2 * pr, tb = ta + 1;
#pragma unroll
    for (int h = 0; h < 2; h++) {
      int tok = ta + h;
      float fv = bfb2f(f_ssm[(size_t)(token0 + tok) * P_ + p]);
      float val = fv * til[tok] * fo;
      float xv[4];
      *reinterpret_cast<float4*>(xv) =
          *reinterpret_cast<const float4*>(x + (size_t)(token0 + tok) * D_ + tid * 4);
      float ss = 0;
#pragma unroll
      for (int a = 0; a < 4; a++) {
        float v = xv[a] + val;
        xa[tok][a] = v;
        ss += v * v;
      }
#pragma unroll
      for (int off = 32; off; off >>= 1) ss += __shfl_down(ss, off);
      if ((tid & 63) == 0) red[tok][tid >> 6] = ss;
    }
    u32 tmp[4];
#pragma unroll
    for (int i = 0; i < 4; i++)
      tmp[i] = packh(xa[ta][i] * gv[i], xa[tb][i] * gv[i]);
    *reinterpret_cast<uint4*>(&h2p[pr][tid * 4]) = *reinterpret_cast<const uint4*>(tmp);
  }
  __syncthreads();

  float invt[G_];
#pragma unroll
  for (int tok = 0; tok < G_; tok++) {
    float s = 0;
#pragma unroll
    for (int w = 0; w < 8; w++) s += red[tok][w];
    invt[tok] = rsqrtf(s * (1.0f / D_) + EPS_);
  }

  // ---- MLP gather: one neuron per thread, pk_fma over token pairs ----
  union { int4 v[4]; int s[16]; } iu;
  union { uint4 v[4]; u32 s[16]; } wd;
  {
    const int4* ip = reinterpret_cast<const int4*>(idx + p * K_);
    const uint4* wp = reinterpret_cast<const uint4*>(wgd + p * K_);
#pragma unroll
    for (int q = 0; q < 4; q++) { iu.v[q] = ip[q]; wd.v[q] = wp[q]; }
  }
  float wqm = wq_m[p];
  float fom = fo_m[p];

#pragma unroll
  for (int pr = 0; pr < 2; pr++) {
    h2t acc = {(_Float16)0.0f, (_Float16)0.0f};
#pragma unroll
    for (int k = 0; k < K_; k++) acc = pkfma(h2p[pr][iu.s[k]], wd.s[k], acc);
#pragma unroll
    for (int h = 0; h < 2; h++) {
      int tok = 2 * pr + h;
      float a = h ? (float)acc.y : (float)acc.x;
      float u = wqm * invt[tok] * a;
      float f = sigmoidf_(u);
      float val = f * u * fom;
      float ov[4];
#pragma unroll
      for (int a2 = 0; a2 < 4; a2++) ov[a2] = xa[tok][a2] + val;
      *reinterpret_cast<float4*>(out + (size_t)(token0 + tok) * D_ + tid * 4) =
          *reinterpret_cast<const float4*>(ov);
    }
  }
}

// ---------------- host ----------------
extern "C" void kernel_launch(void* const* d_in, const int* in_sizes, int n_in,
                              void* d_out, int out_size, void* d_ws, size_t ws_size,
                              hipStream_t stream) {
  const float* x     = (const float*)d_in[0];
  const float* state = (const float*)d_in[1];
  const float* g1    = (const float*)d_in[2];
  const float* g2    = (const float*)d_in[3];
  const int*   idx_s = (const int*)d_in[4];
  const float* wg_s  = (const float*)d_in[5];
  const int*   idx_m = (const int*)d_in[6];
  const float* wg_m  = (const float*)d_in[7];
  const float* Wp_s  = (const float*)d_in[8];
  const float* Wo_s  = (const float*)d_in[9];
  const float* Wp_m  = (const float*)d_in[10];
  const float* Wo_m  = (const float*)d_in[11];
  const float* U     = (const float*)d_in[12];
  const float* V     = (const float*)d_in[13];
  const float* Wgt   = (const float*)d_in[14];
  const float* bg    = (const float*)d_in[15];
  float* out = (float*)d_out;

  char* ws = (char*)d_ws;
  float* wq_s = (float*)(ws + 0);          // 2 KB
  float* fo_s = (float*)(ws + 2048);
  float* wq_m = (float*)(ws + 4096);
  float* fo_m = (float*)(ws + 6144);
  u32* Ud     = (u32*)(ws + 8192);                     // 64 KB f16x2-dup U  [P][R]
  u32* Wd     = (u32*)(ws + 8192 + 65536);             // 64 KB f16x2-dup Wgt[P][R]
  u32* wgd_s  = (u32*)(ws + 8192 + 131072);            // 32 KB f16x2-dup wg_s
  u32* wgd_m  = (u32*)(ws + 8192 + 163840);            // 32 KB f16x2-dup wg_m
  size_t off = 8192 + 196608;
  u16* f_ssm = (u16*)(ws + off); off += (size_t)B_ * T_ * P_ * 2;    // 8 MB bf16
  float* z   = (float*)(ws + off); off += (size_t)B_ * R_ * T_ * 4;  // 1 MB
  float* lam = (float*)(ws + off); off += (size_t)B_ * R_ * T_ * 4;  // 1 MB
  float* S   = (float*)(ws + off);                                   // 1 MB

  hipLaunchKernelGGL(k_scalars, dim3(2), dim3(256), 0, stream,
                     Wp_s, Wo_s, Wp_m, Wo_m, U, Wgt, wg_s, wg_m,
                     wq_s, fo_s, wq_m, fo_m, Ud, Wd, wgd_s, wgd_m);
  hipLaunchKernelGGL(k_phase1, dim3(B_ * T_ / G_), dim3(512), 0, stream,
                     x, g1, idx_s, wgd_s, Ud, Wd, bg, wq_s, f_ssm, z, lam);
  hipLaunchKernelGGL(k_scan, dim3(B_ * R_), dim3(64), 0, stream,
                     z, lam, state, S, out + (size_t)B_ * T_ * D_);
  hipLaunchKernelGGL(k_phase3, dim3(B_ * T_ / G_), dim3(512), 0, stream,
                     x, g2, idx_m, wgd_m, V, S, f_ssm, fo_s, wq_m, fo_m, out);
}